// Round 4
// baseline (602.616 us; speedup 1.0000x reference)
//
#include <hip/hip_runtime.h>
#include <hip/hip_bf16.h>

#define NN 50000
#define NE 1200000
#define H 64
#define NB 782            // node buckets of 64 nodes
#define NSTRIPE 8
#define NSB (NB * NSTRIPE)

// ---------------------------------------------------------------------------
// k0: fold small weights.
//   We2[2][64] = We @ Wm1_e ; bp = be@Wm1_e + bm1
//   Wma[64][64]= Wm2 @ Wu1_agg ; bma = bm2 @ Wu1_agg
// ---------------------------------------------------------------------------
__global__ __launch_bounds__(256) void k0_prep(
    const float* __restrict__ We, const float* __restrict__ be,
    const float* __restrict__ Wm1, const float* __restrict__ bm1,
    const float* __restrict__ Wm2, const float* __restrict__ bm2,
    const float* __restrict__ Wu1,
    float* __restrict__ We2, float* __restrict__ bp,
    float* __restrict__ Wma, float* __restrict__ bma)
{
    const int tid = threadIdx.x;
    const int j = tid & (H - 1);
    const int q = tid >> 6;   // 0..3
    if (q == 0) {
        float s0 = 0.f, s1 = 0.f, sb = 0.f;
        for (int k = 0; k < H; ++k) {
            const float w = Wm1[(2 * H + k) * H + j];
            s0 = fmaf(We[k], w, s0);
            s1 = fmaf(We[H + k], w, s1);
            sb = fmaf(be[k], w, sb);
        }
        We2[j]     = s0;
        We2[H + j] = s1;
        bp[j]      = sb + bm1[j];
        float sm = 0.f;
        for (int l = 0; l < H; ++l)
            sm = fmaf(bm2[l], Wu1[(H + l) * H + j], sm);
        bma[j] = sm;
    }
    for (int k = q * (H / 4); k < (q + 1) * (H / 4); ++k) {
        float s = 0.f;
        for (int l = 0; l < H; ++l)
            s = fmaf(Wm2[k * H + l], Wu1[(H + l) * H + j], s);
        Wma[k * H + j] = s;
    }
}

// ---------------------------------------------------------------------------
// k1: per-node. h = relu(x@Wn1+bn1)@Wn2+bn2 ; A = h@Wm1_dst (f32) ;
//     B = h@Wm1_src (bf16) ; HU = h@Wu1_h (bf16). One wave per node.
// ---------------------------------------------------------------------------
__global__ __launch_bounds__(256) void k1_node(
    const float* __restrict__ x,
    const float* __restrict__ Wn1, const float* __restrict__ bn1,
    const float* __restrict__ Wn2, const float* __restrict__ bn2,
    const float* __restrict__ Wm1, const float* __restrict__ Wu1,
    float* __restrict__ A, unsigned short* __restrict__ Bb,
    unsigned short* __restrict__ HUb)
{
    __shared__ float sWn2[H * H];
    __shared__ float sW1d[H * H];
    __shared__ float sW1s[H * H];
    __shared__ float sh1[4][H];
    __shared__ float sh[4][H];
    const int tid = threadIdx.x;
    for (int i = tid; i < H * H; i += 256) {
        sWn2[i] = Wn2[i];
        sW1d[i] = Wm1[i];             // rows 0..63  (dst part)
        sW1s[i] = Wm1[H * H + i];     // rows 64..127 (src part)
    }
    __syncthreads();
    const int w = tid >> 6, j = tid & 63;
    float wn1k[5];
#pragma unroll
    for (int k = 0; k < 5; ++k) wn1k[k] = Wn1[k * H + j];
    const float b1 = bn1[j], b2 = bn2[j];
    const int stride = gridDim.x * 4;
    for (int n = blockIdx.x * 4 + w; n < NN; n += stride) {
        float h1 = b1;
#pragma unroll
        for (int k = 0; k < 5; ++k) h1 = fmaf(x[n * 5 + k], wn1k[k], h1);
        h1 = fmaxf(h1, 0.f);
        sh1[w][j] = h1;
        __builtin_amdgcn_wave_barrier();
        float hv = b2;
#pragma unroll 16
        for (int k = 0; k < H; ++k) hv = fmaf(sh1[w][k], sWn2[k * H + j], hv);
        sh[w][j] = hv;
        __builtin_amdgcn_wave_barrier();
        float a = 0.f, bb = 0.f, hu = 0.f;
#pragma unroll 8
        for (int k = 0; k < H; ++k) {
            const float hk = sh[w][k];
            a  = fmaf(hk, sW1d[k * H + j], a);
            bb = fmaf(hk, sW1s[k * H + j], bb);
            hu = fmaf(hk, Wu1[k * H + j], hu);   // L1-resident (16 KB)
        }
        A[(size_t)n * H + j] = a;
        __hip_bfloat16 hb = __float2bfloat16(bb);
        Bb[(size_t)n * H + j] = *reinterpret_cast<unsigned short*>(&hb);
        __hip_bfloat16 hu16 = __float2bfloat16(hu);
        HUb[(size_t)n * H + j] = *reinterpret_cast<unsigned short*>(&hu16);
        __builtin_amdgcn_wave_barrier();
    }
}

// ---------------------------------------------------------------------------
// k2i: init sub-bucket cursors to their base record index
// ---------------------------------------------------------------------------
__global__ __launch_bounds__(256) void k2i_init(int* __restrict__ cursor, int cap)
{
    const int i = blockIdx.x * 256 + threadIdx.x;
    if (i < NSB) cursor[i] = i * cap;
}

// ---------------------------------------------------------------------------
// k2c: bucketed append scatter. bucket = dst>>6, stripe = blockIdx&7 (XCD).
// Record (12B): { src | (dst&63)<<16, bits(ea.x), bits(ea.y) }.
// Appends within a sub-bucket are position-adjacent and same-XCD -> L2
// write-combining -> ~payload-only write traffic.
// ---------------------------------------------------------------------------
__global__ __launch_bounds__(256) void k2c_scatter(
    const int* __restrict__ eidx, const float* __restrict__ ea,
    int* __restrict__ cursor, int3* __restrict__ rec, int cap)
{
    const int e = blockIdx.x * 256 + threadIdx.x;
    if (e >= NE) return;
    const int dst = eidx[NE + e];
    const int src = eidx[e];
    const float2 q = ((const float2*)ea)[e];
    const int key = (dst >> 6) * NSTRIPE + (blockIdx.x & (NSTRIPE - 1));
    const int pos = atomicAdd(&cursor[key], 1);
    if (pos - key * cap < cap) {
        int3 r;
        r.x = src | ((dst & 63) << 16);
        r.y = __float_as_int(q.x);
        r.z = __float_as_int(q.y);
        rec[pos] = r;
    }
}

// ---------------------------------------------------------------------------
// k3_walk: one block per 64-node bucket. Stage (A+bp) tile in LDS, walk the
// 8 record runs, accumulate relu(msg) into LDS f32 accumulators (ds_add),
// count edges per node, then flush Rsum -> R (=d_out scratch) and cnt.
// ---------------------------------------------------------------------------
__global__ __launch_bounds__(256) void k3_walk(
    const int* __restrict__ cursor, const int3* __restrict__ rec,
    const float* __restrict__ A, const unsigned short* __restrict__ Bb,
    const float* __restrict__ We2, const float* __restrict__ bp,
    int cap, float* __restrict__ R, float* __restrict__ cnt)
{
    __shared__ float sA[64 * H];     // A row + bp, per local node
    __shared__ float Racc[64 * H];
    __shared__ int   cntL[64];
    const int tid = threadIdx.x;
    const int b = blockIdx.x;
    for (int i = tid; i < 64 * H; i += 256) {
        const int n = b * 64 + (i >> 6);
        sA[i] = (n < NN ? A[(size_t)b * (64 * H) + i] : 0.f) + bp[i & 63];
        Racc[i] = 0.f;
    }
    if (tid < 64) cntL[tid] = 0;
    __syncthreads();

    const int w = tid >> 6, j = tid & 63;
    const float w0 = We2[j], w1 = We2[H + j];

    auto process = [&](int idx) {
        const int3 rr = rec[idx];
        const int src = rr.x & 0xFFFF;
        const int ld  = (rr.x >> 16) & 63;
        const float bb = __uint_as_float((unsigned)Bb[(size_t)src * H + j] << 16);
        float z = sA[ld * H + j] + bb;
        z = fmaf(__int_as_float(rr.y), w0, z);
        z = fmaf(__int_as_float(rr.z), w1, z);
        z = fmaxf(z, 0.f);
        if (z > 0.f) atomicAdd(&Racc[ld * H + j], z);
        if (j == 0)  atomicAdd(&cntL[ld], 1);
    };

    for (int r = 0; r < NSTRIPE; ++r) {
        const int kb = b * NSTRIPE + r;
        const int base = kb * cap;
        int cr = cursor[kb] - base;
        if (cr > cap) cr = cap;
        int i = w;
        for (; i + 12 < cr; i += 16) {
            process(base + i);
            process(base + i + 4);
            process(base + i + 8);
            process(base + i + 12);
        }
        for (; i < cr; i += 4) process(base + i);
    }
    __syncthreads();

    for (int i = tid; i < 64 * H; i += 256) {
        const int n = b * 64 + (i >> 6);
        if (n < NN) R[(size_t)b * (64 * H) + i] = Racc[i];
    }
    if (tid < 64) {
        const int n = b * 64 + tid;
        if (n < NN) cnt[n] = (float)cntL[tid];
    }
}

// ---------------------------------------------------------------------------
// k4_final: per-node epilogue (R read from `out` in place).
//   s = R[n]@Wma ; z = HU[n] + (s + cnt*bma)/max(cnt,1) + bu1
//   out = relu(z)@Wu2 + bu2
// ---------------------------------------------------------------------------
__global__ __launch_bounds__(256) void k4_final(
    const float* __restrict__ cnt,
    const unsigned short* __restrict__ HUb,
    const float* __restrict__ Wma, const float* __restrict__ bma,
    const float* __restrict__ bu1,
    const float* __restrict__ Wu2, const float* __restrict__ bu2,
    float* __restrict__ out)
{
    __shared__ float sWma[H * H];
    __shared__ float sWu2[H * H];
    __shared__ float sr[4][H];
    __shared__ float st[4][H];
    const int tid = threadIdx.x;
    for (int i = tid; i < H * H; i += 256) {
        sWma[i] = Wma[i];
        sWu2[i] = Wu2[i];
    }
    __syncthreads();
    const int w = tid >> 6, j = tid & 63;
    const float bmaj = bma[j], bu1j = bu1[j], bu2j = bu2[j];
    const int stride = gridDim.x * 4;
    for (int n = blockIdx.x * 4 + w; n < NN; n += stride) {
        sr[w][j] = out[(size_t)n * H + j];   // R row (in-place scratch)
        __builtin_amdgcn_wave_barrier();
        float s = 0.f;
#pragma unroll 16
        for (int k = 0; k < H; ++k) s = fmaf(sr[w][k], sWma[k * H + j], s);
        const float c = cnt[n];
        const float cc = fmaxf(c, 1.0f);
        const float hu = __uint_as_float((unsigned)HUb[(size_t)n * H + j] << 16);
        float z = hu + (s + c * bmaj) / cc + bu1j;
        z = fmaxf(z, 0.f);
        st[w][j] = z;
        __builtin_amdgcn_wave_barrier();
        float o = bu2j;
#pragma unroll 16
        for (int k = 0; k < H; ++k) o = fmaf(st[w][k], sWu2[k * H + j], o);
        out[(size_t)n * H + j] = o;
        __builtin_amdgcn_wave_barrier();
    }
}

// ---------------------------------------------------------------------------
extern "C" void kernel_launch(void* const* d_in, const int* in_sizes, int n_in,
                              void* d_out, int out_size, void* d_ws, size_t ws_size,
                              hipStream_t stream) {
    (void)in_sizes; (void)n_in; (void)out_size;
    const float* x    = (const float*)d_in[0];
    const float* eatt = (const float*)d_in[1];
    const int*   eidx = (const int*)d_in[2];
    const float* Wn1  = (const float*)d_in[3];
    const float* bn1  = (const float*)d_in[4];
    const float* Wn2  = (const float*)d_in[5];
    const float* bn2  = (const float*)d_in[6];
    const float* We   = (const float*)d_in[7];
    const float* be   = (const float*)d_in[8];
    const float* Wm1  = (const float*)d_in[9];
    const float* bm1  = (const float*)d_in[10];
    const float* Wm2  = (const float*)d_in[11];
    const float* bm2  = (const float*)d_in[12];
    const float* Wu1  = (const float*)d_in[13];
    const float* bu1  = (const float*)d_in[14];
    const float* Wu2  = (const float*)d_in[15];
    const float* bu2  = (const float*)d_in[16];
    float* out = (float*)d_out;

    char* wsb = (char*)d_ws;
    float* A    = (float*)wsb;                               // NN*H f32
    unsigned short* Bb  = (unsigned short*)(A + (size_t)NN * H);   // NN*H bf16
    unsigned short* HUb = Bb + (size_t)NN * H;                     // NN*H bf16
    float* cnt  = (float*)(HUb + (size_t)NN * H);            // NN f32
    int*   curs = (int*)(cnt + NN);                          // NSB
    float* We2  = (float*)(curs + NSB);                      // 2*H
    float* bp   = We2 + 2 * H;                               // H
    float* Wma  = bp + H;                                    // H*H
    float* bma  = Wma + H * H;                               // H
    size_t fixed_bytes = (size_t)((char*)(bma + H) - wsb);
    fixed_bytes = (fixed_bytes + 15) & ~(size_t)15;
    int3* rec = (int3*)(wsb + fixed_bytes);

    // capacity per sub-bucket from remaining workspace (target 288 = λ+6.9σ)
    long long avail = (long long)ws_size - (long long)fixed_bytes;
    int cap = (int)(avail / ((long long)NSB * 12));
    if (cap > 288) cap = 288;
    if (cap < 64)  cap = 64;   // would overflow; nothing better available

    k0_prep<<<1, 256, 0, stream>>>(We, be, Wm1, bm1, Wm2, bm2, Wu1,
                                   We2, bp, Wma, bma);
    k1_node<<<1024, 256, 0, stream>>>(x, Wn1, bn1, Wn2, bn2, Wm1, Wu1,
                                      A, Bb, HUb);
    k2i_init<<<(NSB + 255) / 256, 256, 0, stream>>>(curs, cap);
    k2c_scatter<<<(NE + 255) / 256, 256, 0, stream>>>(eidx, eatt, curs, rec, cap);
    k3_walk<<<NB, 256, 0, stream>>>(curs, rec, A, Bb, We2, bp, cap, out, cnt);
    k4_final<<<1024, 256, 0, stream>>>(cnt, HUb, Wma, bma, bu1, Wu2, bu2, out);
}

// Round 5
// 350.770 us; speedup vs baseline: 1.7180x; 1.7180x over previous
//
#include <hip/hip_runtime.h>
#include <hip/hip_bf16.h>

#define NN 50000
#define NE 1200000
#define H 64
#define NB 782            // node buckets of 64 nodes
#define NSTRIPE 8
#define NSB (NB * NSTRIPE)

// ---------------------------------------------------------------------------
// k0: fold small weights.
//   We2[2][64] = We @ Wm1_e ; bp = be@Wm1_e + bm1
//   Wma[64][64]= Wm2 @ Wu1_agg ; bma = bm2 @ Wu1_agg
// ---------------------------------------------------------------------------
__global__ __launch_bounds__(256) void k0_prep(
    const float* __restrict__ We, const float* __restrict__ be,
    const float* __restrict__ Wm1, const float* __restrict__ bm1,
    const float* __restrict__ Wm2, const float* __restrict__ bm2,
    const float* __restrict__ Wu1,
    float* __restrict__ We2, float* __restrict__ bp,
    float* __restrict__ Wma, float* __restrict__ bma)
{
    const int tid = threadIdx.x;
    const int j = tid & (H - 1);
    const int q = tid >> 6;   // 0..3
    if (q == 0) {
        float s0 = 0.f, s1 = 0.f, sb = 0.f;
        for (int k = 0; k < H; ++k) {
            const float w = Wm1[(2 * H + k) * H + j];
            s0 = fmaf(We[k], w, s0);
            s1 = fmaf(We[H + k], w, s1);
            sb = fmaf(be[k], w, sb);
        }
        We2[j]     = s0;
        We2[H + j] = s1;
        bp[j]      = sb + bm1[j];
        float sm = 0.f;
        for (int l = 0; l < H; ++l)
            sm = fmaf(bm2[l], Wu1[(H + l) * H + j], sm);
        bma[j] = sm;
    }
    for (int k = q * (H / 4); k < (q + 1) * (H / 4); ++k) {
        float s = 0.f;
        for (int l = 0; l < H; ++l)
            s = fmaf(Wm2[k * H + l], Wu1[(H + l) * H + j], s);
        Wma[k * H + j] = s;
    }
}

// ---------------------------------------------------------------------------
// k1: per-node. h = relu(x@Wn1+bn1)@Wn2+bn2 ; A = h@Wm1_dst (f32) ;
//     B = h@Wm1_src (bf16) ; HU = h@Wu1_h (bf16). One wave per node.
// ---------------------------------------------------------------------------
__global__ __launch_bounds__(256) void k1_node(
    const float* __restrict__ x,
    const float* __restrict__ Wn1, const float* __restrict__ bn1,
    const float* __restrict__ Wn2, const float* __restrict__ bn2,
    const float* __restrict__ Wm1, const float* __restrict__ Wu1,
    float* __restrict__ A, unsigned short* __restrict__ Bb,
    unsigned short* __restrict__ HUb)
{
    __shared__ float sWn2[H * H];
    __shared__ float sW1d[H * H];
    __shared__ float sW1s[H * H];
    __shared__ float sh1[4][H];
    __shared__ float sh[4][H];
    const int tid = threadIdx.x;
    for (int i = tid; i < H * H; i += 256) {
        sWn2[i] = Wn2[i];
        sW1d[i] = Wm1[i];             // rows 0..63  (dst part)
        sW1s[i] = Wm1[H * H + i];     // rows 64..127 (src part)
    }
    __syncthreads();
    const int w = tid >> 6, j = tid & 63;
    float wn1k[5];
#pragma unroll
    for (int k = 0; k < 5; ++k) wn1k[k] = Wn1[k * H + j];
    const float b1 = bn1[j], b2 = bn2[j];
    const int stride = gridDim.x * 4;
    for (int n = blockIdx.x * 4 + w; n < NN; n += stride) {
        float h1 = b1;
#pragma unroll
        for (int k = 0; k < 5; ++k) h1 = fmaf(x[n * 5 + k], wn1k[k], h1);
        h1 = fmaxf(h1, 0.f);
        sh1[w][j] = h1;
        __builtin_amdgcn_wave_barrier();
        float hv = b2;
#pragma unroll 16
        for (int k = 0; k < H; ++k) hv = fmaf(sh1[w][k], sWn2[k * H + j], hv);
        sh[w][j] = hv;
        __builtin_amdgcn_wave_barrier();
        float a = 0.f, bb = 0.f, hu = 0.f;
#pragma unroll 8
        for (int k = 0; k < H; ++k) {
            const float hk = sh[w][k];
            a  = fmaf(hk, sW1d[k * H + j], a);
            bb = fmaf(hk, sW1s[k * H + j], bb);
            hu = fmaf(hk, Wu1[k * H + j], hu);   // L1-resident (16 KB)
        }
        A[(size_t)n * H + j] = a;
        __hip_bfloat16 hb = __float2bfloat16(bb);
        Bb[(size_t)n * H + j] = *reinterpret_cast<unsigned short*>(&hb);
        __hip_bfloat16 hu16 = __float2bfloat16(hu);
        HUb[(size_t)n * H + j] = *reinterpret_cast<unsigned short*>(&hu16);
        __builtin_amdgcn_wave_barrier();
    }
}

// ---------------------------------------------------------------------------
// k2i: init sub-bucket cursors to their base record index
// ---------------------------------------------------------------------------
__global__ __launch_bounds__(256) void k2i_init(int* __restrict__ cursor, int cap)
{
    const int i = blockIdx.x * 256 + threadIdx.x;
    if (i < NSB) cursor[i] = i * cap;
}

// ---------------------------------------------------------------------------
// k2c: bucketed append scatter. bucket = dst>>6, stripe = blockIdx&7.
// 8-byte record: { src | (dst&63)<<16 , bf16(ea.x) | bf16(ea.y)<<16 }.
// ---------------------------------------------------------------------------
__global__ __launch_bounds__(256) void k2c_scatter(
    const int* __restrict__ eidx, const float* __restrict__ ea,
    int* __restrict__ cursor, uint2* __restrict__ rec, int cap)
{
    const int e = blockIdx.x * 256 + threadIdx.x;
    if (e >= NE) return;
    const int dst = eidx[NE + e];
    const int src = eidx[e];
    const float2 q = ((const float2*)ea)[e];
    const int key = (dst >> 6) * NSTRIPE + (blockIdx.x & (NSTRIPE - 1));
    const int pos = atomicAdd(&cursor[key], 1);
    if (pos - key * cap < cap) {
        __hip_bfloat16 bx = __float2bfloat16(q.x);
        __hip_bfloat16 by = __float2bfloat16(q.y);
        uint2 r;
        r.x = (unsigned)src | ((unsigned)(dst & 63) << 16);
        r.y = (unsigned)*reinterpret_cast<unsigned short*>(&bx)
            | ((unsigned)*reinterpret_cast<unsigned short*>(&by) << 16);
        rec[pos] = r;
    }
}

// ---------------------------------------------------------------------------
// k2h: per-bucket histogram from records (no global atomics) -> cnt_i
// ---------------------------------------------------------------------------
__global__ __launch_bounds__(256) void k2h_hist(
    const int* __restrict__ cursor, const uint2* __restrict__ rec,
    int cap, int* __restrict__ cnt_i)
{
    __shared__ int cntL[64];
    const int tid = threadIdx.x;
    const int b = blockIdx.x;
    if (tid < 64) cntL[tid] = 0;
    __syncthreads();
    for (int r = 0; r < NSTRIPE; ++r) {
        const int kb = b * NSTRIPE + r;
        const int base = kb * cap;
        int cr = cursor[kb] - base;
        if (cr > cap) cr = cap;
        for (int i = tid; i < cr; i += 256) {
            const int ld = (rec[base + i].x >> 16) & 63;
            atomicAdd(&cntL[ld], 1);
        }
    }
    __syncthreads();
    if (tid < 64) {
        const int n = b * 64 + tid;
        if (n < NN) cnt_i[n] = cntL[tid];
    }
}

// ---------------------------------------------------------------------------
// Hierarchical scan (3 kernels): off[] = exclusive scan of cnt_i
// ---------------------------------------------------------------------------
__global__ __launch_bounds__(256) void k2b_scan1(
    const int* __restrict__ cnt_i, int* __restrict__ off, int* __restrict__ bsum)
{
    __shared__ int wsum[4];
    const int tid = threadIdx.x;
    const int lane = tid & 63, wv = tid >> 6;
    const int base = blockIdx.x * 1024 + tid * 4;
    int v0 = (base + 0 < NN) ? cnt_i[base + 0] : 0;
    int v1 = (base + 1 < NN) ? cnt_i[base + 1] : 0;
    int v2 = (base + 2 < NN) ? cnt_i[base + 2] : 0;
    int v3 = (base + 3 < NN) ? cnt_i[base + 3] : 0;
    const int t0 = v0, t1 = t0 + v1, t2 = t1 + v2, t3 = t2 + v3;
    int s = t3;
#pragma unroll
    for (int d = 1; d < 64; d <<= 1) {
        int t = __shfl_up(s, (unsigned)d, 64);
        if (lane >= d) s += t;
    }
    if (lane == 63) wsum[wv] = s;
    __syncthreads();
    int wbase = 0;
#pragma unroll
    for (int k = 0; k < 4; ++k) wbase += (k < wv) ? wsum[k] : 0;
    const int excl = wbase + (s - t3);
    if (base + 0 < NN) off[base + 0] = excl;
    if (base + 1 < NN) off[base + 1] = excl + t0;
    if (base + 2 < NN) off[base + 2] = excl + t1;
    if (base + 3 < NN) off[base + 3] = excl + t2;
    if (tid == 0) bsum[blockIdx.x] = wsum[0] + wsum[1] + wsum[2] + wsum[3];
}

__global__ __launch_bounds__(64) void k2b_scan2(
    const int* __restrict__ bsum, int* __restrict__ bsumX)
{
    const int lane = threadIdx.x;
    const int v = (lane < 49) ? bsum[lane] : 0;
    int s = v;
#pragma unroll
    for (int d = 1; d < 64; d <<= 1) {
        int t = __shfl_up(s, (unsigned)d, 64);
        if (lane >= d) s += t;
    }
    if (lane < 49) bsumX[lane] = s - v;
}

__global__ __launch_bounds__(256) void k2b_scan3(
    int* __restrict__ off, const int* __restrict__ bsumX)
{
    const int add = bsumX[blockIdx.x];
    const int base = blockIdx.x * 1024 + threadIdx.x * 4;
#pragma unroll
    for (int k = 0; k < 4; ++k) {
        const int i = base + k;
        if (i < NN) off[i] += add;
    }
    if (blockIdx.x == 0 && threadIdx.x == 0) off[NN] = NE;
}

// ---------------------------------------------------------------------------
// k2d: per-bucket compaction to exact CSR. The bucket's CSR window is a
// dense contiguous region -> scattered writes cover full lines.
// rec2: { src , bf16(ea.x)|bf16(ea.y)<<16 }
// ---------------------------------------------------------------------------
__global__ __launch_bounds__(256) void k2d_compact(
    const int* __restrict__ cursor, const uint2* __restrict__ rec,
    const int* __restrict__ off, int cap, uint2* __restrict__ rec2)
{
    __shared__ int cur[64];
    const int tid = threadIdx.x;
    const int b = blockIdx.x;
    if (tid < 64) {
        const int n = b * 64 + tid;
        cur[tid] = (n < NN) ? off[n] : 0;
    }
    __syncthreads();
    for (int r = 0; r < NSTRIPE; ++r) {
        const int kb = b * NSTRIPE + r;
        const int base = kb * cap;
        int cr = cursor[kb] - base;
        if (cr > cap) cr = cap;
        for (int i = tid; i < cr; i += 256) {
            const uint2 rr = rec[base + i];
            const int ld = (rr.x >> 16) & 63;
            const int pos = atomicAdd(&cur[ld], 1);
            uint2 r2;
            r2.x = rr.x & 0xFFFFu;
            r2.y = rr.y;
            rec2[pos] = r2;
        }
    }
}

// ---------------------------------------------------------------------------
// k3_agg: one wave per dst node, exact CSR. rsum accumulated in registers,
// fused update MLP -> out.  cnt = off[n+1]-off[n].
// ---------------------------------------------------------------------------
__global__ __launch_bounds__(256) void k3_agg(
    const int* __restrict__ off, const uint2* __restrict__ rec2,
    const float* __restrict__ A, const unsigned short* __restrict__ Bb,
    const unsigned short* __restrict__ HUb,
    const float* __restrict__ We2, const float* __restrict__ bp,
    const float* __restrict__ Wma, const float* __restrict__ bma,
    const float* __restrict__ bu1,
    const float* __restrict__ Wu2, const float* __restrict__ bu2,
    float* __restrict__ out)
{
    __shared__ float sWma[H * H];
    __shared__ float sWu2[H * H];
    __shared__ float sr[4][H];
    __shared__ float st[4][H];
    const int tid = threadIdx.x;
    for (int i = tid; i < H * H; i += 256) {
        sWma[i] = Wma[i];
        sWu2[i] = Wu2[i];
    }
    __syncthreads();
    const int w = tid >> 6, j = tid & 63;
    const float w0 = We2[j], w1 = We2[H + j], b = bp[j];
    const float bmaj = bma[j], bu1j = bu1[j], bu2j = bu2[j];
    const int stride = gridDim.x * 4;
    for (int n = blockIdx.x * 4 + w; n < NN; n += stride) {
        const int e0 = __builtin_amdgcn_readfirstlane(off[n]);
        const int e1 = __builtin_amdgcn_readfirstlane(off[n + 1]);
        const float a = A[(size_t)n * H + j] + b;
        float rsum = 0.f;
        int e = e0;
        for (; e + 4 <= e1; e += 4) {
            const uint2 r0 = rec2[e], r1 = rec2[e + 1], r2 = rec2[e + 2], r3 = rec2[e + 3];
            const float bb0 = __uint_as_float((unsigned)Bb[(size_t)r0.x * H + j] << 16);
            const float bb1 = __uint_as_float((unsigned)Bb[(size_t)r1.x * H + j] << 16);
            const float bb2 = __uint_as_float((unsigned)Bb[(size_t)r2.x * H + j] << 16);
            const float bb3 = __uint_as_float((unsigned)Bb[(size_t)r3.x * H + j] << 16);
            float z0 = a + bb0;
            z0 = fmaf(__uint_as_float(r0.y << 16), w0, z0);
            z0 = fmaf(__uint_as_float(r0.y & 0xFFFF0000u), w1, z0);
            float z1 = a + bb1;
            z1 = fmaf(__uint_as_float(r1.y << 16), w0, z1);
            z1 = fmaf(__uint_as_float(r1.y & 0xFFFF0000u), w1, z1);
            float z2 = a + bb2;
            z2 = fmaf(__uint_as_float(r2.y << 16), w0, z2);
            z2 = fmaf(__uint_as_float(r2.y & 0xFFFF0000u), w1, z2);
            float z3 = a + bb3;
            z3 = fmaf(__uint_as_float(r3.y << 16), w0, z3);
            z3 = fmaf(__uint_as_float(r3.y & 0xFFFF0000u), w1, z3);
            rsum += fmaxf(z0, 0.f) + fmaxf(z1, 0.f) + fmaxf(z2, 0.f) + fmaxf(z3, 0.f);
        }
        for (; e < e1; ++e) {
            const uint2 r0 = rec2[e];
            const float bb0 = __uint_as_float((unsigned)Bb[(size_t)r0.x * H + j] << 16);
            float z0 = a + bb0;
            z0 = fmaf(__uint_as_float(r0.y << 16), w0, z0);
            z0 = fmaf(__uint_as_float(r0.y & 0xFFFF0000u), w1, z0);
            rsum += fmaxf(z0, 0.f);
        }
        sr[w][j] = rsum;
        __builtin_amdgcn_wave_barrier();
        float s = 0.f;
#pragma unroll 16
        for (int k = 0; k < H; ++k) s = fmaf(sr[w][k], sWma[k * H + j], s);
        const float c = (float)(e1 - e0);
        const float cc = fmaxf(c, 1.0f);
        const float hu = __uint_as_float((unsigned)HUb[(size_t)n * H + j] << 16);
        float z = hu + (s + c * bmaj) / cc + bu1j;
        z = fmaxf(z, 0.f);
        st[w][j] = z;
        __builtin_amdgcn_wave_barrier();
        float o = bu2j;
#pragma unroll 16
        for (int k = 0; k < H; ++k) o = fmaf(st[w][k], sWu2[k * H + j], o);
        out[(size_t)n * H + j] = o;
        __builtin_amdgcn_wave_barrier();
    }
}

// ---------------------------------------------------------------------------
extern "C" void kernel_launch(void* const* d_in, const int* in_sizes, int n_in,
                              void* d_out, int out_size, void* d_ws, size_t ws_size,
                              hipStream_t stream) {
    (void)in_sizes; (void)n_in; (void)out_size;
    const float* x    = (const float*)d_in[0];
    const float* eatt = (const float*)d_in[1];
    const int*   eidx = (const int*)d_in[2];
    const float* Wn1  = (const float*)d_in[3];
    const float* bn1  = (const float*)d_in[4];
    const float* Wn2  = (const float*)d_in[5];
    const float* bn2  = (const float*)d_in[6];
    const float* We   = (const float*)d_in[7];
    const float* be   = (const float*)d_in[8];
    const float* Wm1  = (const float*)d_in[9];
    const float* bm1  = (const float*)d_in[10];
    const float* Wm2  = (const float*)d_in[11];
    const float* bm2  = (const float*)d_in[12];
    const float* Wu1  = (const float*)d_in[13];
    const float* bu1  = (const float*)d_in[14];
    const float* Wu2  = (const float*)d_in[15];
    const float* bu2  = (const float*)d_in[16];
    float* out = (float*)d_out;

    char* wsb = (char*)d_ws;
    float* A    = (float*)wsb;                                     // NN*H f32
    unsigned short* Bb  = (unsigned short*)(A + (size_t)NN * H);   // NN*H bf16
    unsigned short* HUb = Bb + (size_t)NN * H;                     // NN*H bf16
    uint2* rec2 = (uint2*)(HUb + (size_t)NN * H);                  // NE*8B
    int*   off  = (int*)(rec2 + NE);                               // NN+1
    int*   cnti = off + NN + 1;                                    // NN
    int*   curs = cnti + NN;                                       // NSB
    int*   bsum = curs + NSB;                                      // 64
    int*   bsumX= bsum + 64;                                       // 64
    float* We2  = (float*)(bsumX + 64);                            // 2*H
    float* bp   = We2 + 2 * H;                                     // H
    float* Wma  = bp + H;                                          // H*H
    float* bma  = Wma + H * H;                                     // H
    size_t fixed_bytes = (size_t)((char*)(bma + H) - wsb);
    fixed_bytes = (fixed_bytes + 15) & ~(size_t)15;
    uint2* rec = (uint2*)(wsb + fixed_bytes);

    // sub-bucket capacity from remaining ws; need >= 288 (lambda=192 +6.9sig,
    // proven no-overflow at 288 in round 4)
    long long avail = (long long)ws_size - (long long)fixed_bytes;
    int cap = (int)(avail / ((long long)NSB * 8));
    if (cap > 512) cap = 512;
    if (cap < 96)  cap = 96;

    k0_prep<<<1, 256, 0, stream>>>(We, be, Wm1, bm1, Wm2, bm2, Wu1,
                                   We2, bp, Wma, bma);
    k1_node<<<1024, 256, 0, stream>>>(x, Wn1, bn1, Wn2, bn2, Wm1, Wu1,
                                      A, Bb, HUb);
    k2i_init<<<(NSB + 255) / 256, 256, 0, stream>>>(curs, cap);
    k2c_scatter<<<(NE + 255) / 256, 256, 0, stream>>>(eidx, eatt, curs, rec, cap);
    k2h_hist<<<NB, 256, 0, stream>>>(curs, rec, cap, cnti);
    k2b_scan1<<<49, 256, 0, stream>>>(cnti, off, bsum);
    k2b_scan2<<<1, 64, 0, stream>>>(bsum, bsumX);
    k2b_scan3<<<49, 256, 0, stream>>>(off, bsumX);
    k2d_compact<<<NB, 256, 0, stream>>>(curs, rec, off, cap, rec2);
    k3_agg<<<1024, 256, 0, stream>>>(off, rec2, A, Bb, HUb, We2, bp, Wma, bma,
                                     bu1, Wu2, bu2, out);
}

// Round 6
// 341.087 us; speedup vs baseline: 1.7668x; 1.0284x over previous
//
#include <hip/hip_runtime.h>
#include <hip/hip_bf16.h>

#define NN 50000
#define NE 1200000
#define H 64
#define NB 782            // node buckets of 64 nodes
#define NSTRIPE 8
#define NSB (NB * NSTRIPE)

using bf16x8 = __attribute__((ext_vector_type(8))) short;
using f32x4  = __attribute__((ext_vector_type(4))) float;

static __device__ __forceinline__ unsigned short f2bf(float f) {
    __hip_bfloat16 h = __float2bfloat16(f);
    return *reinterpret_cast<unsigned short*>(&h);
}

// ---------------------------------------------------------------------------
// k0: fold small weights.
//   We2[2][64] = We @ Wm1_e ; bp = be@Wm1_e + bm1
//   Wma[64][64]= Wm2 @ Wu1_agg ; bma = bm2 @ Wu1_agg
// ---------------------------------------------------------------------------
__global__ __launch_bounds__(256) void k0_prep(
    const float* __restrict__ We, const float* __restrict__ be,
    const float* __restrict__ Wm1, const float* __restrict__ bm1,
    const float* __restrict__ Wm2, const float* __restrict__ bm2,
    const float* __restrict__ Wu1,
    float* __restrict__ We2, float* __restrict__ bp,
    float* __restrict__ Wma, float* __restrict__ bma)
{
    const int tid = threadIdx.x;
    const int j = tid & (H - 1);
    const int q = tid >> 6;   // 0..3
    if (q == 0) {
        float s0 = 0.f, s1 = 0.f, sb = 0.f;
        for (int k = 0; k < H; ++k) {
            const float w = Wm1[(2 * H + k) * H + j];
            s0 = fmaf(We[k], w, s0);
            s1 = fmaf(We[H + k], w, s1);
            sb = fmaf(be[k], w, sb);
        }
        We2[j]     = s0;
        We2[H + j] = s1;
        bp[j]      = sb + bm1[j];
        float sm = 0.f;
        for (int l = 0; l < H; ++l)
            sm = fmaf(bm2[l], Wu1[(H + l) * H + j], sm);
        bma[j] = sm;
    }
    for (int k = q * (H / 4); k < (q + 1) * (H / 4); ++k) {
        float s = 0.f;
        for (int l = 0; l < H; ++l)
            s = fmaf(Wm2[k * H + l], Wu1[(H + l) * H + j], s);
        Wma[k * H + j] = s;
    }
}

// ---------------------------------------------------------------------------
// k1_mfma: per-node encoder + 4 projections, all on matrix cores.
//   h1 = relu(x@Wn1+bn1)  [16x64 tile via MFMA, K padded 5->32]
//   h  = h1@Wn2+bn2
//   A  = h@Wm1_dst (f32) ; Bb = bf16(h@Wm1_src) ; HUb = bf16(h@Wu1_h)
// One wave per 16-node group. Weights pre-gathered into LDS in per-lane
// fragment layout (lane-contiguous b128 reads, conflict-free). h staged in a
// per-wave XOR-swizzled LDS buffer.
// MFMA 16x16x32_bf16 layouts: A: lane=16b+r holds A[r][8b+j]; B: lane=16b+c
// holds B[8b+j][c]; C/D: col=lane&15, row=(lane>>4)*4+reg.
// ---------------------------------------------------------------------------
__global__ __launch_bounds__(256) void k1_mfma(
    const float* __restrict__ x,
    const float* __restrict__ Wn1, const float* __restrict__ bn1,
    const float* __restrict__ Wn2, const float* __restrict__ bn2,
    const float* __restrict__ Wm1, const float* __restrict__ Wu1,
    float* __restrict__ A, unsigned short* __restrict__ Bb,
    unsigned short* __restrict__ HUb)
{
    __shared__ unsigned short hbuf[4][16 * 64];     // 8 KB, per-wave tiles
    __shared__ bf16x8 wfrag[4][4][2][64];           // 32 KB [mat][t][kh][lane]

    const int tid = threadIdx.x;
    const int w   = tid >> 6;
    const int l   = tid & 63;
    const int l15 = l & 15;
    const int lb  = l >> 4;   // 0..3

    // ---- init: wave w gathers matrix w into fragment layout -------------
    const float* Wmats[4] = { Wn2, Wm1, Wm1 + H * H, Wu1 };
    const float* Wsrc = Wmats[w];
#pragma unroll
    for (int t = 0; t < 4; ++t)
#pragma unroll
        for (int kh = 0; kh < 2; ++kh) {
            bf16x8 f;
#pragma unroll
            for (int j = 0; j < 8; ++j) {
                const int k = kh * 32 + lb * 8 + j;
                f[j] = (short)f2bf(Wsrc[k * H + 16 * t + l15]);
            }
            wfrag[w][t][kh][l] = f;
        }

    // stage-1 weight fragments (Wn1 padded K=5->32) kept in registers
    bf16x8 b1frag[4];
    float bn1t[4], bn2t[4];
#pragma unroll
    for (int t = 0; t < 4; ++t) {
        bn1t[t] = bn1[16 * t + l15];
        bn2t[t] = bn2[16 * t + l15];
#pragma unroll
        for (int j = 0; j < 8; ++j) {
            float v = (lb == 0 && j < 5) ? Wn1[j * H + 16 * t + l15] : 0.f;
            b1frag[t][j] = (short)f2bf(v);
        }
    }
    __syncthreads();

    const int g = blockIdx.x * 4 + w;       // 16-node group id
    if (g * 16 >= NN) return;
    const int n0 = g * 16;

    const f32x4 z4 = {0.f, 0.f, 0.f, 0.f};

    // ---- stage 1: h1 = relu(x@Wn1+bn1) ----------------------------------
    bf16x8 xf = {0, 0, 0, 0, 0, 0, 0, 0};
    if (lb == 0) {
        const float* xr = x + (size_t)(n0 + l15) * 5;
#pragma unroll
        for (int j = 0; j < 5; ++j) xf[j] = (short)f2bf(xr[j]);
    }
    f32x4 acc1[4];
#pragma unroll
    for (int t = 0; t < 4; ++t)
        acc1[t] = __builtin_amdgcn_mfma_f32_16x16x32_bf16(xf, b1frag[t], z4, 0, 0, 0);
#pragma unroll
    for (int t = 0; t < 4; ++t)
#pragma unroll
        for (int q = 0; q < 4; ++q) {
            const int m = lb * 4 + q;
            const int idx = (m * 64 + 16 * t + l15) ^ ((m & 7) << 3);
            hbuf[w][idx] = f2bf(fmaxf(acc1[t][q] + bn1t[t], 0.f));
        }
    __builtin_amdgcn_wave_barrier();

    // A-fragment reader from the swizzled h tile
    auto rdA = [&](int kh) {
        const int idx = (l15 * 64 + kh * 32 + lb * 8) ^ ((l15 & 7) << 3);
        return *reinterpret_cast<const bf16x8*>(&hbuf[w][idx]);
    };

    // ---- stage 2: h = h1@Wn2 + bn2 --------------------------------------
    {
        bf16x8 a0 = rdA(0), a1 = rdA(1);
        __builtin_amdgcn_wave_barrier();
        f32x4 acc[4];
#pragma unroll
        for (int t = 0; t < 4; ++t) {
            acc[t] = __builtin_amdgcn_mfma_f32_16x16x32_bf16(a0, wfrag[0][t][0][l], z4, 0, 0, 0);
            acc[t] = __builtin_amdgcn_mfma_f32_16x16x32_bf16(a1, wfrag[0][t][1][l], acc[t], 0, 0, 0);
        }
#pragma unroll
        for (int t = 0; t < 4; ++t)
#pragma unroll
            for (int q = 0; q < 4; ++q) {
                const int m = lb * 4 + q;
                const int idx = (m * 64 + 16 * t + l15) ^ ((m & 7) << 3);
                hbuf[w][idx] = f2bf(acc[t][q] + bn2t[t]);
            }
        __builtin_amdgcn_wave_barrier();
    }

    // ---- stage 3: three projections of h --------------------------------
    bf16x8 h0 = rdA(0), h1v = rdA(1);

#pragma unroll
    for (int t = 0; t < 4; ++t) {      // A = h@Wm1_dst (f32)
        f32x4 acc = __builtin_amdgcn_mfma_f32_16x16x32_bf16(h0, wfrag[1][t][0][l], z4, 0, 0, 0);
        acc = __builtin_amdgcn_mfma_f32_16x16x32_bf16(h1v, wfrag[1][t][1][l], acc, 0, 0, 0);
#pragma unroll
        for (int q = 0; q < 4; ++q) {
            const int row = lb * 4 + q;
            A[(size_t)(n0 + row) * H + 16 * t + l15] = acc[q];
        }
    }
#pragma unroll
    for (int t = 0; t < 4; ++t) {      // Bb = bf16(h@Wm1_src)
        f32x4 acc = __builtin_amdgcn_mfma_f32_16x16x32_bf16(h0, wfrag[2][t][0][l], z4, 0, 0, 0);
        acc = __builtin_amdgcn_mfma_f32_16x16x32_bf16(h1v, wfrag[2][t][1][l], acc, 0, 0, 0);
#pragma unroll
        for (int q = 0; q < 4; ++q) {
            const int row = lb * 4 + q;
            Bb[(size_t)(n0 + row) * H + 16 * t + l15] = f2bf(acc[q]);
        }
    }
#pragma unroll
    for (int t = 0; t < 4; ++t) {      // HUb = bf16(h@Wu1_h)
        f32x4 acc = __builtin_amdgcn_mfma_f32_16x16x32_bf16(h0, wfrag[3][t][0][l], z4, 0, 0, 0);
        acc = __builtin_amdgcn_mfma_f32_16x16x32_bf16(h1v, wfrag[3][t][1][l], acc, 0, 0, 0);
#pragma unroll
        for (int q = 0; q < 4; ++q) {
            const int row = lb * 4 + q;
            HUb[(size_t)(n0 + row) * H + 16 * t + l15] = f2bf(acc[q]);
        }
    }
}

// ---------------------------------------------------------------------------
// k2i: init sub-bucket cursors to their base record index
// ---------------------------------------------------------------------------
__global__ __launch_bounds__(256) void k2i_init(int* __restrict__ cursor, int cap)
{
    const int i = blockIdx.x * 256 + threadIdx.x;
    if (i < NSB) cursor[i] = i * cap;
}

// ---------------------------------------------------------------------------
// k2c: bucketed append scatter + fused dst histogram.
// 8-byte record: { src | (dst&63)<<16 , bf16(ea.x) | bf16(ea.y)<<16 }.
// ---------------------------------------------------------------------------
__global__ __launch_bounds__(256) void k2c_scatter(
    const int* __restrict__ eidx, const float* __restrict__ ea,
    int* __restrict__ cursor, uint2* __restrict__ rec, int cap,
    int* __restrict__ cnt_i)
{
    const int e = blockIdx.x * 256 + threadIdx.x;
    if (e >= NE) return;
    const int dst = eidx[NE + e];
    const int src = eidx[e];
    const float2 q = ((const float2*)ea)[e];
    const int key = (dst >> 6) * NSTRIPE + (blockIdx.x & (NSTRIPE - 1));
    const int pos = atomicAdd(&cursor[key], 1);
    atomicAdd(&cnt_i[dst], 1);
    if (pos - key * cap < cap) {
        uint2 r;
        r.x = (unsigned)src | ((unsigned)(dst & 63) << 16);
        r.y = (unsigned)f2bf(q.x) | ((unsigned)f2bf(q.y) << 16);
        rec[pos] = r;
    }
}

// ---------------------------------------------------------------------------
// Hierarchical scan (3 kernels): off[] = exclusive scan of cnt_i
// ---------------------------------------------------------------------------
__global__ __launch_bounds__(256) void k2b_scan1(
    const int* __restrict__ cnt_i, int* __restrict__ off, int* __restrict__ bsum)
{
    __shared__ int wsum[4];
    const int tid = threadIdx.x;
    const int lane = tid & 63, wv = tid >> 6;
    const int base = blockIdx.x * 1024 + tid * 4;
    int v0 = (base + 0 < NN) ? cnt_i[base + 0] : 0;
    int v1 = (base + 1 < NN) ? cnt_i[base + 1] : 0;
    int v2 = (base + 2 < NN) ? cnt_i[base + 2] : 0;
    int v3 = (base + 3 < NN) ? cnt_i[base + 3] : 0;
    const int t0 = v0, t1 = t0 + v1, t2 = t1 + v2, t3 = t2 + v3;
    int s = t3;
#pragma unroll
    for (int d = 1; d < 64; d <<= 1) {
        int t = __shfl_up(s, (unsigned)d, 64);
        if (lane >= d) s += t;
    }
    if (lane == 63) wsum[wv] = s;
    __syncthreads();
    int wbase = 0;
#pragma unroll
    for (int k = 0; k < 4; ++k) wbase += (k < wv) ? wsum[k] : 0;
    const int excl = wbase + (s - t3);
    if (base + 0 < NN) off[base + 0] = excl;
    if (base + 1 < NN) off[base + 1] = excl + t0;
    if (base + 2 < NN) off[base + 2] = excl + t1;
    if (base + 3 < NN) off[base + 3] = excl + t2;
    if (tid == 0) bsum[blockIdx.x] = wsum[0] + wsum[1] + wsum[2] + wsum[3];
}

__global__ __launch_bounds__(64) void k2b_scan2(
    const int* __restrict__ bsum, int* __restrict__ bsumX)
{
    const int lane = threadIdx.x;
    const int v = (lane < 49) ? bsum[lane] : 0;
    int s = v;
#pragma unroll
    for (int d = 1; d < 64; d <<= 1) {
        int t = __shfl_up(s, (unsigned)d, 64);
        if (lane >= d) s += t;
    }
    if (lane < 49) bsumX[lane] = s - v;
}

__global__ __launch_bounds__(256) void k2b_scan3(
    int* __restrict__ off, const int* __restrict__ bsumX)
{
    const int add = bsumX[blockIdx.x];
    const int base = blockIdx.x * 1024 + threadIdx.x * 4;
#pragma unroll
    for (int k = 0; k < 4; ++k) {
        const int i = base + k;
        if (i < NN) off[i] += add;
    }
    if (blockIdx.x == 0 && threadIdx.x == 0) off[NN] = NE;
}

// ---------------------------------------------------------------------------
// k2d: per-bucket compaction to exact CSR. rec2: { src , bf16 ea pair }
// ---------------------------------------------------------------------------
__global__ __launch_bounds__(256) void k2d_compact(
    const int* __restrict__ cursor, const uint2* __restrict__ rec,
    const int* __restrict__ off, int cap, uint2* __restrict__ rec2)
{
    __shared__ int cur[64];
    const int tid = threadIdx.x;
    const int b = blockIdx.x;
    if (tid < 64) {
        const int n = b * 64 + tid;
        cur[tid] = (n < NN) ? off[n] : 0;
    }
    __syncthreads();
    for (int r = 0; r < NSTRIPE; ++r) {
        const int kb = b * NSTRIPE + r;
        const int base = kb * cap;
        int cr = cursor[kb] - base;
        if (cr > cap) cr = cap;
        for (int i = tid; i < cr; i += 256) {
            const uint2 rr = rec[base + i];
            const int ld = (rr.x >> 16) & 63;
            const int pos = atomicAdd(&cur[ld], 1);
            uint2 r2;
            r2.x = rr.x & 0xFFFFu;
            r2.y = rr.y;
            rec2[pos] = r2;
        }
    }
}

// ---------------------------------------------------------------------------
// k3_agg: one wave per dst node, exact CSR. rsum accumulated in registers,
// fused update MLP -> out.  cnt = off[n+1]-off[n].
// ---------------------------------------------------------------------------
__global__ __launch_bounds__(256) void k3_agg(
    const int* __restrict__ off, const uint2* __restrict__ rec2,
    const float* __restrict__ A, const unsigned short* __restrict__ Bb,
    const unsigned short* __restrict__ HUb,
    const float* __restrict__ We2, const float* __restrict__ bp,
    const float* __restrict__ Wma, const float* __restrict__ bma,
    const float* __restrict__ bu1,
    const float* __restrict__ Wu2, const float* __restrict__ bu2,
    float* __restrict__ out)
{
    __shared__ float sWma[H * H];
    __shared__ float sWu2[H * H];
    __shared__ float sr[4][H];
    __shared__ float st[4][H];
    const int tid = threadIdx.x;
    for (int i = tid; i < H * H; i += 256) {
        sWma[i] = Wma[i];
        sWu2[i] = Wu2[i];
    }
    __syncthreads();
    const int w = tid >> 6, j = tid & 63;
    const float w0 = We2[j], w1 = We2[H + j], b = bp[j];
    const float bmaj = bma[j], bu1j = bu1[j], bu2j = bu2[j];
    const int stride = gridDim.x * 4;
    for (int n = blockIdx.x * 4 + w; n < NN; n += stride) {
        const int e0 = __builtin_amdgcn_readfirstlane(off[n]);
        const int e1 = __builtin_amdgcn_readfirstlane(off[n + 1]);
        const float a = A[(size_t)n * H + j] + b;
        float rsum = 0.f;
        int e = e0;
        for (; e + 4 <= e1; e += 4) {
            const uint2 r0 = rec2[e], r1 = rec2[e + 1], r2 = rec2[e + 2], r3 = rec2[e + 3];
            const float bb0 = __uint_as_float((unsigned)Bb[(size_t)r0.x * H + j] << 16);
            const float bb1 = __uint_as_float((unsigned)Bb[(size_t)r1.x * H + j] << 16);
            const float bb2 = __uint_as_float((unsigned)Bb[(size_t)r2.x * H + j] << 16);
            const float bb3 = __uint_as_float((unsigned)Bb[(size_t)r3.x * H + j] << 16);
            float z0 = a + bb0;
            z0 = fmaf(__uint_as_float(r0.y << 16), w0, z0);
            z0 = fmaf(__uint_as_float(r0.y & 0xFFFF0000u), w1, z0);
            float z1 = a + bb1;
            z1 = fmaf(__uint_as_float(r1.y << 16), w0, z1);
            z1 = fmaf(__uint_as_float(r1.y & 0xFFFF0000u), w1, z1);
            float z2 = a + bb2;
            z2 = fmaf(__uint_as_float(r2.y << 16), w0, z2);
            z2 = fmaf(__uint_as_float(r2.y & 0xFFFF0000u), w1, z2);
            float z3 = a + bb3;
            z3 = fmaf(__uint_as_float(r3.y << 16), w0, z3);
            z3 = fmaf(__uint_as_float(r3.y & 0xFFFF0000u), w1, z3);
            rsum += fmaxf(z0, 0.f) + fmaxf(z1, 0.f) + fmaxf(z2, 0.f) + fmaxf(z3, 0.f);
        }
        for (; e < e1; ++e) {
            const uint2 r0 = rec2[e];
            const float bb0 = __uint_as_float((unsigned)Bb[(size_t)r0.x * H + j] << 16);
            float z0 = a + bb0;
            z0 = fmaf(__uint_as_float(r0.y << 16), w0, z0);
            z0 = fmaf(__uint_as_float(r0.y & 0xFFFF0000u), w1, z0);
            rsum += fmaxf(z0, 0.f);
        }
        sr[w][j] = rsum;
        __builtin_amdgcn_wave_barrier();
        float s = 0.f;
#pragma unroll 16
        for (int k = 0; k < H; ++k) s = fmaf(sr[w][k], sWma[k * H + j], s);
        const float c = (float)(e1 - e0);
        const float cc = fmaxf(c, 1.0f);
        const float hu = __uint_as_float((unsigned)HUb[(size_t)n * H + j] << 16);
        float z = hu + (s + c * bmaj) / cc + bu1j;
        z = fmaxf(z, 0.f);
        st[w][j] = z;
        __builtin_amdgcn_wave_barrier();
        float o = bu2j;
#pragma unroll 16
        for (int k = 0; k < H; ++k) o = fmaf(st[w][k], sWu2[k * H + j], o);
        out[(size_t)n * H + j] = o;
        __builtin_amdgcn_wave_barrier();
    }
}

// ---------------------------------------------------------------------------
extern "C" void kernel_launch(void* const* d_in, const int* in_sizes, int n_in,
                              void* d_out, int out_size, void* d_ws, size_t ws_size,
                              hipStream_t stream) {
    (void)in_sizes; (void)n_in; (void)out_size;
    const float* x    = (const float*)d_in[0];
    const float* eatt = (const float*)d_in[1];
    const int*   eidx = (const int*)d_in[2];
    const float* Wn1  = (const float*)d_in[3];
    const float* bn1  = (const float*)d_in[4];
    const float* Wn2  = (const float*)d_in[5];
    const float* bn2  = (const float*)d_in[6];
    const float* We   = (const float*)d_in[7];
    const float* be   = (const float*)d_in[8];
    const float* Wm1  = (const float*)d_in[9];
    const float* bm1  = (const float*)d_in[10];
    const float* Wm2  = (const float*)d_in[11];
    const float* bm2  = (const float*)d_in[12];
    const float* Wu1  = (const float*)d_in[13];
    const float* bu1  = (const float*)d_in[14];
    const float* Wu2  = (const float*)d_in[15];
    const float* bu2  = (const float*)d_in[16];
    float* out = (float*)d_out;

    char* wsb = (char*)d_ws;
    float* A    = (float*)wsb;                                     // NN*H f32
    unsigned short* Bb  = (unsigned short*)(A + (size_t)NN * H);   // NN*H bf16
    unsigned short* HUb = Bb + (size_t)NN * H;                     // NN*H bf16
    uint2* rec2 = (uint2*)(HUb + (size_t)NN * H);                  // NE*8B
    int*   off  = (int*)(rec2 + NE);                               // NN+1
    int*   cnti = off + NN + 1;                                    // NN
    int*   curs = cnti + NN;                                       // NSB
    int*   bsum = curs + NSB;                                      // 64
    int*   bsumX= bsum + 64;                                       // 64
    float* We2  = (float*)(bsumX + 64);                            // 2*H
    float* bp   = We2 + 2 * H;                                     // H
    float* Wma  = bp + H;                                          // H*H
    float* bma  = Wma + H * H;                                     // H
    size_t fixed_bytes = (size_t)((char*)(bma + H) - wsb);
    fixed_bytes = (fixed_bytes + 15) & ~(size_t)15;
    uint2* rec = (uint2*)(wsb + fixed_bytes);

    long long avail = (long long)ws_size - (long long)fixed_bytes;
    int cap = (int)(avail / ((long long)NSB * 8));
    if (cap > 512) cap = 512;
    if (cap < 96)  cap = 96;

    hipMemsetAsync(cnti, 0, NN * sizeof(int), stream);

    k0_prep<<<1, 256, 0, stream>>>(We, be, Wm1, bm1, Wm2, bm2, Wu1,
                                   We2, bp, Wma, bma);
    k1_mfma<<<(NN / 16 + 3) / 4, 256, 0, stream>>>(x, Wn1, bn1, Wn2, bn2,
                                                   Wm1, Wu1, A, Bb, HUb);
    k2i_init<<<(NSB + 255) / 256, 256, 0, stream>>>(curs, cap);
    k2c_scatter<<<(NE + 255) / 256, 256, 0, stream>>>(eidx, eatt, curs, rec,
                                                      cap, cnti);
    k2b_scan1<<<49, 256, 0, stream>>>(cnti, off, bsum);
    k2b_scan2<<<1, 64, 0, stream>>>(bsum, bsumX);
    k2b_scan3<<<49, 256, 0, stream>>>(off, bsumX);
    k2d_compact<<<NB, 256, 0, stream>>>(curs, rec, off, cap, rec2);
    k3_agg<<<1024, 256, 0, stream>>>(off, rec2, A, Bb, HUb, We2, bp, Wma, bma,
                                     bu1, Wu2, bu2, out);
}

// Round 7
// 288.689 us; speedup vs baseline: 2.0874x; 1.1815x over previous
//
#include <hip/hip_runtime.h>
#include <hip/hip_bf16.h>

#define NN 50000
#define NE 1200000
#define H 64
#define NBUCK 196          // coarse buckets of 256 nodes (dst>>8)
#define CHUNK 4096
#define NCHUNK ((NE + CHUNK - 1) / CHUNK)   // 293

using bf16x8 = __attribute__((ext_vector_type(8))) short;
using f32x4  = __attribute__((ext_vector_type(4))) float;

static __device__ __forceinline__ unsigned short f2bf(float f) {
    __hip_bfloat16 h = __float2bfloat16(f);
    return *reinterpret_cast<unsigned short*>(&h);
}

// ---------------------------------------------------------------------------
// k0: fold small weights.
//   We2[2][64] = We @ Wm1_e ; bp = be@Wm1_e + bm1
//   Wma[64][64]= Wm2 @ Wu1_agg ; bma = bm2 @ Wu1_agg
// ---------------------------------------------------------------------------
__global__ __launch_bounds__(256) void k0_prep(
    const float* __restrict__ We, const float* __restrict__ be,
    const float* __restrict__ Wm1, const float* __restrict__ bm1,
    const float* __restrict__ Wm2, const float* __restrict__ bm2,
    const float* __restrict__ Wu1,
    float* __restrict__ We2, float* __restrict__ bp,
    float* __restrict__ Wma, float* __restrict__ bma)
{
    const int tid = threadIdx.x;
    const int j = tid & (H - 1);
    const int q = tid >> 6;
    if (q == 0) {
        float s0 = 0.f, s1 = 0.f, sb = 0.f;
        for (int k = 0; k < H; ++k) {
            const float w = Wm1[(2 * H + k) * H + j];
            s0 = fmaf(We[k], w, s0);
            s1 = fmaf(We[H + k], w, s1);
            sb = fmaf(be[k], w, sb);
        }
        We2[j]     = s0;
        We2[H + j] = s1;
        bp[j]      = sb + bm1[j];
        float sm = 0.f;
        for (int l = 0; l < H; ++l)
            sm = fmaf(bm2[l], Wu1[(H + l) * H + j], sm);
        bma[j] = sm;
    }
    for (int k = q * (H / 4); k < (q + 1) * (H / 4); ++k) {
        float s = 0.f;
        for (int l = 0; l < H; ++l)
            s = fmaf(Wm2[k * H + l], Wu1[(H + l) * H + j], s);
        Wma[k * H + j] = s;
    }
}

// ---------------------------------------------------------------------------
// k1_mfma: encoder + 4 projections on matrix cores (unchanged from R6).
// ---------------------------------------------------------------------------
__global__ __launch_bounds__(256) void k1_mfma(
    const float* __restrict__ x,
    const float* __restrict__ Wn1, const float* __restrict__ bn1,
    const float* __restrict__ Wn2, const float* __restrict__ bn2,
    const float* __restrict__ Wm1, const float* __restrict__ Wu1,
    float* __restrict__ A, unsigned short* __restrict__ Bb,
    unsigned short* __restrict__ HUb)
{
    __shared__ unsigned short hbuf[4][16 * 64];
    __shared__ bf16x8 wfrag[4][4][2][64];

    const int tid = threadIdx.x;
    const int w   = tid >> 6;
    const int l   = tid & 63;
    const int l15 = l & 15;
    const int lb  = l >> 4;

    const float* Wmats[4] = { Wn2, Wm1, Wm1 + H * H, Wu1 };
    const float* Wsrc = Wmats[w];
#pragma unroll
    for (int t = 0; t < 4; ++t)
#pragma unroll
        for (int kh = 0; kh < 2; ++kh) {
            bf16x8 f;
#pragma unroll
            for (int j = 0; j < 8; ++j) {
                const int k = kh * 32 + lb * 8 + j;
                f[j] = (short)f2bf(Wsrc[k * H + 16 * t + l15]);
            }
            wfrag[w][t][kh][l] = f;
        }

    bf16x8 b1frag[4];
    float bn1t[4], bn2t[4];
#pragma unroll
    for (int t = 0; t < 4; ++t) {
        bn1t[t] = bn1[16 * t + l15];
        bn2t[t] = bn2[16 * t + l15];
#pragma unroll
        for (int j = 0; j < 8; ++j) {
            float v = (lb == 0 && j < 5) ? Wn1[j * H + 16 * t + l15] : 0.f;
            b1frag[t][j] = (short)f2bf(v);
        }
    }
    __syncthreads();

    const int g = blockIdx.x * 4 + w;
    if (g * 16 >= NN) return;
    const int n0 = g * 16;
    const f32x4 z4 = {0.f, 0.f, 0.f, 0.f};

    bf16x8 xf = {0, 0, 0, 0, 0, 0, 0, 0};
    if (lb == 0) {
        const float* xr = x + (size_t)(n0 + l15) * 5;
#pragma unroll
        for (int j = 0; j < 5; ++j) xf[j] = (short)f2bf(xr[j]);
    }
    f32x4 acc1[4];
#pragma unroll
    for (int t = 0; t < 4; ++t)
        acc1[t] = __builtin_amdgcn_mfma_f32_16x16x32_bf16(xf, b1frag[t], z4, 0, 0, 0);
#pragma unroll
    for (int t = 0; t < 4; ++t)
#pragma unroll
        for (int q = 0; q < 4; ++q) {
            const int m = lb * 4 + q;
            const int idx = (m * 64 + 16 * t + l15) ^ ((m & 7) << 3);
            hbuf[w][idx] = f2bf(fmaxf(acc1[t][q] + bn1t[t], 0.f));
        }
    __builtin_amdgcn_wave_barrier();

    auto rdA = [&](int kh) {
        const int idx = (l15 * 64 + kh * 32 + lb * 8) ^ ((l15 & 7) << 3);
        return *reinterpret_cast<const bf16x8*>(&hbuf[w][idx]);
    };

    {
        bf16x8 a0 = rdA(0), a1 = rdA(1);
        __builtin_amdgcn_wave_barrier();
        f32x4 acc[4];
#pragma unroll
        for (int t = 0; t < 4; ++t) {
            acc[t] = __builtin_amdgcn_mfma_f32_16x16x32_bf16(a0, wfrag[0][t][0][l], z4, 0, 0, 0);
            acc[t] = __builtin_amdgcn_mfma_f32_16x16x32_bf16(a1, wfrag[0][t][1][l], acc[t], 0, 0, 0);
        }
#pragma unroll
        for (int t = 0; t < 4; ++t)
#pragma unroll
            for (int q = 0; q < 4; ++q) {
                const int m = lb * 4 + q;
                const int idx = (m * 64 + 16 * t + l15) ^ ((m & 7) << 3);
                hbuf[w][idx] = f2bf(acc[t][q] + bn2t[t]);
            }
        __builtin_amdgcn_wave_barrier();
    }

    bf16x8 h0 = rdA(0), h1v = rdA(1);
#pragma unroll
    for (int t = 0; t < 4; ++t) {
        f32x4 acc = __builtin_amdgcn_mfma_f32_16x16x32_bf16(h0, wfrag[1][t][0][l], z4, 0, 0, 0);
        acc = __builtin_amdgcn_mfma_f32_16x16x32_bf16(h1v, wfrag[1][t][1][l], acc, 0, 0, 0);
#pragma unroll
        for (int q = 0; q < 4; ++q)
            A[(size_t)(n0 + lb * 4 + q) * H + 16 * t + l15] = acc[q];
    }
#pragma unroll
    for (int t = 0; t < 4; ++t) {
        f32x4 acc = __builtin_amdgcn_mfma_f32_16x16x32_bf16(h0, wfrag[2][t][0][l], z4, 0, 0, 0);
        acc = __builtin_amdgcn_mfma_f32_16x16x32_bf16(h1v, wfrag[2][t][1][l], acc, 0, 0, 0);
#pragma unroll
        for (int q = 0; q < 4; ++q)
            Bb[(size_t)(n0 + lb * 4 + q) * H + 16 * t + l15] = f2bf(acc[q]);
    }
#pragma unroll
    for (int t = 0; t < 4; ++t) {
        f32x4 acc = __builtin_amdgcn_mfma_f32_16x16x32_bf16(h0, wfrag[3][t][0][l], z4, 0, 0, 0);
        acc = __builtin_amdgcn_mfma_f32_16x16x32_bf16(h1v, wfrag[3][t][1][l], acc, 0, 0, 0);
#pragma unroll
        for (int q = 0; q < 4; ++q)
            HUb[(size_t)(n0 + lb * 4 + q) * H + 16 * t + l15] = f2bf(acc[q]);
    }
}

// ---------------------------------------------------------------------------
// k2h0: coarse-bucket histogram (LDS-aggregated; ~115K global atomics)
// ---------------------------------------------------------------------------
__global__ __launch_bounds__(256) void k2h0(
    const int* __restrict__ eidx, int* __restrict__ gbcnt)
{
    __shared__ int hl[NBUCK];
    const int tid = threadIdx.x;
    for (int i = tid; i < NBUCK; i += 256) hl[i] = 0;
    __syncthreads();
    const int stride = gridDim.x * 256;
    for (int e = blockIdx.x * 256 + tid; e < NE; e += stride)
        atomicAdd(&hl[eidx[NE + e] >> 8], 1);
    __syncthreads();
    for (int i = tid; i < NBUCK; i += 256)
        if (hl[i]) atomicAdd(&gbcnt[i], hl[i]);
}

// ---------------------------------------------------------------------------
// k2h1: single-block scan of bucket counts -> bbase[NBUCK+1], gcur[]
// ---------------------------------------------------------------------------
__global__ __launch_bounds__(256) void k2h1(
    const int* __restrict__ gbcnt, int* __restrict__ bbase, int* __restrict__ gcur)
{
    __shared__ int wsum[4];
    const int tid = threadIdx.x, lane = tid & 63, wv = tid >> 6;
    const int v = (tid < NBUCK) ? gbcnt[tid] : 0;
    int s = v;
#pragma unroll
    for (int d = 1; d < 64; d <<= 1) {
        int t = __shfl_up(s, (unsigned)d, 64);
        if (lane >= d) s += t;
    }
    if (lane == 63) wsum[wv] = s;
    __syncthreads();
    int wb = 0;
#pragma unroll
    for (int k = 0; k < 4; ++k) wb += (k < wv) ? wsum[k] : 0;
    const int excl = wb + s - v;
    if (tid < NBUCK) {
        bbase[tid] = excl;
        gcur[tid]  = excl;
        if (tid == NBUCK - 1) bbase[NBUCK] = excl + v;
    }
}

// ---------------------------------------------------------------------------
// k2s: chunk counting-sort. One block per 4096-edge chunk: LDS histogram,
// LDS scan, in-LDS sort, one global cursor atomic per bucket, then flush
// bucket-sorted runs (avg 168B contiguous) -> near-1x write amplification.
// Record: { src | local<<16 | bucket<<24 , bf16(ea.x) | bf16(ea.y)<<16 }
// ---------------------------------------------------------------------------
__global__ __launch_bounds__(256) void k2s_sort(
    const int* __restrict__ eidx, const float* __restrict__ ea,
    int* __restrict__ gcur, uint2* __restrict__ rec)
{
    __shared__ int hcnt[256], delta[256], c2[256];
    __shared__ int wsum[4];
    __shared__ uint2 srt[CHUNK];
    const int tid = threadIdx.x, lane = tid & 63, wv = tid >> 6;
    const int cbase = blockIdx.x * CHUNK;
    const int nck = (NE - cbase < CHUNK) ? (NE - cbase) : CHUNK;

    hcnt[tid] = 0;
    __syncthreads();

    unsigned rx[16], ry[16];
#pragma unroll
    for (int k = 0; k < 16; ++k) {
        const int i = k * 256 + tid;
        if (i < nck) {
            const int e = cbase + i;
            const int dst = eidx[NE + e];
            const int src = eidx[e];
            const float2 q = ((const float2*)ea)[e];
            rx[k] = (unsigned)src | ((unsigned)(dst & 255) << 16)
                  | ((unsigned)(dst >> 8) << 24);
            ry[k] = (unsigned)f2bf(q.x) | ((unsigned)f2bf(q.y) << 16);
            atomicAdd(&hcnt[dst >> 8], 1);
        } else rx[k] = 0xFFFFFFFFu;
    }
    __syncthreads();

    // exclusive scan of hcnt -> start; reserve global space; delta = base-start
    const int v = hcnt[tid];
    int s = v;
#pragma unroll
    for (int d = 1; d < 64; d <<= 1) {
        int t = __shfl_up(s, (unsigned)d, 64);
        if (lane >= d) s += t;
    }
    if (lane == 63) wsum[wv] = s;
    __syncthreads();
    int wb = 0;
#pragma unroll
    for (int k = 0; k < 4; ++k) wb += (k < wv) ? wsum[k] : 0;
    const int excl = wb + s - v;
    c2[tid] = excl;
    if (tid < NBUCK) {
        const int base = v ? atomicAdd(&gcur[tid], v) : 0;
        delta[tid] = base - excl;
    }
    __syncthreads();

    // in-LDS sort by bucket
#pragma unroll
    for (int k = 0; k < 16; ++k) {
        if (rx[k] != 0xFFFFFFFFu) {
            const int b = rx[k] >> 24;
            const int slot = atomicAdd(&c2[b], 1);
            srt[slot] = (uint2){rx[k], ry[k]};
        }
    }
    __syncthreads();

    // linear flush: sorted index i -> global rec[i + delta[bucket]]
    for (int i = tid; i < nck; i += 256) {
        const uint2 rr = srt[i];
        rec[i + delta[rr.x >> 24]] = rr;
    }
}

// ---------------------------------------------------------------------------
// k2d: per-coarse-bucket exact CSR. LDS histogram of 256 local nodes, LDS
// scan -> off[] written directly, then scatter into the bucket's dense
// window (L2-local, full line coverage). rec2: { src , bf16 ea pair }.
// ---------------------------------------------------------------------------
__global__ __launch_bounds__(256) void k2d_csr(
    const int* __restrict__ bbase, const uint2* __restrict__ rec,
    int* __restrict__ off, uint2* __restrict__ rec2)
{
    __shared__ int hl[256], c2[256];
    __shared__ int wsum[4];
    const int tid = threadIdx.x, lane = tid & 63, wv = tid >> 6;
    const int b = blockIdx.x;
    const int r0 = bbase[b], r1 = bbase[b + 1];
    const int nr = r1 - r0;

    hl[tid] = 0;
    __syncthreads();
    for (int i = tid; i < nr; i += 256)
        atomicAdd(&hl[(rec[r0 + i].x >> 16) & 255], 1);
    __syncthreads();

    const int v = hl[tid];
    int s = v;
#pragma unroll
    for (int d = 1; d < 64; d <<= 1) {
        int t = __shfl_up(s, (unsigned)d, 64);
        if (lane >= d) s += t;
    }
    if (lane == 63) wsum[wv] = s;
    __syncthreads();
    int wb = 0;
#pragma unroll
    for (int k = 0; k < 4; ++k) wb += (k < wv) ? wsum[k] : 0;
    const int excl = wb + s - v;
    c2[tid] = r0 + excl;
    const int n = b * 256 + tid;
    if (n < NN) off[n] = r0 + excl;
    if (b == NBUCK - 1 && tid == 0) off[NN] = NE;
    __syncthreads();

    for (int i = tid; i < nr; i += 256) {
        const uint2 rr = rec[r0 + i];
        const int ln = (rr.x >> 16) & 255;
        const int pos = atomicAdd(&c2[ln], 1);
        rec2[pos] = (uint2){rr.x & 0xFFFFu, rr.y};
    }
}

// ---------------------------------------------------------------------------
// k3_agg: one wave per dst node, exact CSR; register accumulation + fused
// update MLP -> out.  cnt = off[n+1]-off[n].
// ---------------------------------------------------------------------------
__global__ __launch_bounds__(256) void k3_agg(
    const int* __restrict__ off, const uint2* __restrict__ rec2,
    const float* __restrict__ A, const unsigned short* __restrict__ Bb,
    const unsigned short* __restrict__ HUb,
    const float* __restrict__ We2, const float* __restrict__ bp,
    const float* __restrict__ Wma, const float* __restrict__ bma,
    const float* __restrict__ bu1,
    const float* __restrict__ Wu2, const float* __restrict__ bu2,
    float* __restrict__ out)
{
    __shared__ float sWma[H * H];
    __shared__ float sWu2[H * H];
    __shared__ float sr[4][H];
    __shared__ float st[4][H];
    const int tid = threadIdx.x;
    for (int i = tid; i < H * H; i += 256) {
        sWma[i] = Wma[i];
        sWu2[i] = Wu2[i];
    }
    __syncthreads();
    const int w = tid >> 6, j = tid & 63;
    const float w0 = We2[j], w1 = We2[H + j], b = bp[j];
    const float bmaj = bma[j], bu1j = bu1[j], bu2j = bu2[j];
    const int stride = gridDim.x * 4;
    for (int n = blockIdx.x * 4 + w; n < NN; n += stride) {
        const int e0 = __builtin_amdgcn_readfirstlane(off[n]);
        const int e1 = __builtin_amdgcn_readfirstlane(off[n + 1]);
        const float a = A[(size_t)n * H + j] + b;
        float rsum = 0.f;
        int e = e0;
        for (; e + 4 <= e1; e += 4) {
            const uint2 r0 = rec2[e], r1 = rec2[e + 1], r2 = rec2[e + 2], r3 = rec2[e + 3];
            const float bb0 = __uint_as_float((unsigned)Bb[(size_t)r0.x * H + j] << 16);
            const float bb1 = __uint_as_float((unsigned)Bb[(size_t)r1.x * H + j] << 16);
            const float bb2 = __uint_as_float((unsigned)Bb[(size_t)r2.x * H + j] << 16);
            const float bb3 = __uint_as_float((unsigned)Bb[(size_t)r3.x * H + j] << 16);
            float z0 = a + bb0;
            z0 = fmaf(__uint_as_float(r0.y << 16), w0, z0);
            z0 = fmaf(__uint_as_float(r0.y & 0xFFFF0000u), w1, z0);
            float z1 = a + bb1;
            z1 = fmaf(__uint_as_float(r1.y << 16), w0, z1);
            z1 = fmaf(__uint_as_float(r1.y & 0xFFFF0000u), w1, z1);
            float z2 = a + bb2;
            z2 = fmaf(__uint_as_float(r2.y << 16), w0, z2);
            z2 = fmaf(__uint_as_float(r2.y & 0xFFFF0000u), w1, z2);
            float z3 = a + bb3;
            z3 = fmaf(__uint_as_float(r3.y << 16), w0, z3);
            z3 = fmaf(__uint_as_float(r3.y & 0xFFFF0000u), w1, z3);
            rsum += fmaxf(z0, 0.f) + fmaxf(z1, 0.f) + fmaxf(z2, 0.f) + fmaxf(z3, 0.f);
        }
        for (; e < e1; ++e) {
            const uint2 r0 = rec2[e];
            const float bb0 = __uint_as_float((unsigned)Bb[(size_t)r0.x * H + j] << 16);
            float z0 = a + bb0;
            z0 = fmaf(__uint_as_float(r0.y << 16), w0, z0);
            z0 = fmaf(__uint_as_float(r0.y & 0xFFFF0000u), w1, z0);
            rsum += fmaxf(z0, 0.f);
        }
        sr[w][j] = rsum;
        __builtin_amdgcn_wave_barrier();
        float s = 0.f;
#pragma unroll 16
        for (int k = 0; k < H; ++k) s = fmaf(sr[w][k], sWma[k * H + j], s);
        const float c = (float)(e1 - e0);
        const float cc = fmaxf(c, 1.0f);
        const float hu = __uint_as_float((unsigned)HUb[(size_t)n * H + j] << 16);
        float z = hu + (s + c * bmaj) / cc + bu1j;
        z = fmaxf(z, 0.f);
        st[w][j] = z;
        __builtin_amdgcn_wave_barrier();
        float o = bu2j;
#pragma unroll 16
        for (int k = 0; k < H; ++k) o = fmaf(st[w][k], sWu2[k * H + j], o);
        out[(size_t)n * H + j] = o;
        __builtin_amdgcn_wave_barrier();
    }
}

// ---------------------------------------------------------------------------
extern "C" void kernel_launch(void* const* d_in, const int* in_sizes, int n_in,
                              void* d_out, int out_size, void* d_ws, size_t ws_size,
                              hipStream_t stream) {
    (void)in_sizes; (void)n_in; (void)out_size; (void)ws_size;
    const float* x    = (const float*)d_in[0];
    const float* eatt = (const float*)d_in[1];
    const int*   eidx = (const int*)d_in[2];
    const float* Wn1  = (const float*)d_in[3];
    const float* bn1  = (const float*)d_in[4];
    const float* Wn2  = (const float*)d_in[5];
    const float* bn2  = (const float*)d_in[6];
    const float* We   = (const float*)d_in[7];
    const float* be   = (const float*)d_in[8];
    const float* Wm1  = (const float*)d_in[9];
    const float* bm1  = (const float*)d_in[10];
    const float* Wm2  = (const float*)d_in[11];
    const float* bm2  = (const float*)d_in[12];
    const float* Wu1  = (const float*)d_in[13];
    const float* bu1  = (const float*)d_in[14];
    const float* Wu2  = (const float*)d_in[15];
    const float* bu2  = (const float*)d_in[16];
    float* out = (float*)d_out;

    char* wsb = (char*)d_ws;
    float* A    = (float*)wsb;                                     // NN*H f32
    unsigned short* Bb  = (unsigned short*)(A + (size_t)NN * H);   // NN*H bf16
    unsigned short* HUb = Bb + (size_t)NN * H;                     // NN*H bf16
    uint2* rec  = (uint2*)(HUb + (size_t)NN * H);                  // NE*8B
    uint2* rec2 = rec + NE;                                        // NE*8B
    int*   off  = (int*)(rec2 + NE);                               // NN+1
    int*   bbase= off + NN + 1;                                    // NBUCK+1
    int*   gbcnt= bbase + NBUCK + 1;                               // NBUCK
    int*   gcur = gbcnt + NBUCK;                                   // NBUCK
    float* We2  = (float*)(gcur + NBUCK);                          // 2*H
    float* bp   = We2 + 2 * H;                                     // H
    float* Wma  = bp + H;                                          // H*H
    float* bma  = Wma + H * H;                                     // H

    hipMemsetAsync(gbcnt, 0, NBUCK * sizeof(int), stream);

    k0_prep<<<1, 256, 0, stream>>>(We, be, Wm1, bm1, Wm2, bm2, Wu1,
                                   We2, bp, Wma, bma);
    k1_mfma<<<(NN / 16 + 3) / 4, 256, 0, stream>>>(x, Wn1, bn1, Wn2, bn2,
                                                   Wm1, Wu1, A, Bb, HUb);
    k2h0<<<1024, 256, 0, stream>>>(eidx, gbcnt);
    k2h1<<<1, 256, 0, stream>>>(gbcnt, bbase, gcur);
    k2s_sort<<<NCHUNK, 256, 0, stream>>>(eidx, eatt, gcur, rec);
    k2d_csr<<<NBUCK, 256, 0, stream>>>(bbase, rec, off, rec2);
    k3_agg<<<1024, 256, 0, stream>>>(off, rec2, A, Bb, HUb, We2, bp, Wma, bma,
                                     bu1, Wu2, bu2, out);
}

// Round 9
// 250.318 us; speedup vs baseline: 2.4074x; 1.1533x over previous
//
#include <hip/hip_runtime.h>
#include <hip/hip_bf16.h>

#define NN 50000
#define NE 1200000
#define H 64
#define NBUCK 196          // coarse buckets of 256 nodes (dst>>8)
#define CHUNK 4096
#define NCHUNK ((NE + CHUNK - 1) / CHUNK)   // 293

using bf16x8 = __attribute__((ext_vector_type(8))) short;
using f32x4  = __attribute__((ext_vector_type(4))) float;

static __device__ __forceinline__ unsigned short f2bf(float f) {
    __hip_bfloat16 h = __float2bfloat16(f);
    return *reinterpret_cast<unsigned short*>(&h);
}
static __device__ __forceinline__ float bf2f(unsigned short u) {
    return __uint_as_float((unsigned)u << 16);
}

// ---------------------------------------------------------------------------
// k0: fold small weights.
// ---------------------------------------------------------------------------
__global__ __launch_bounds__(256) void k0_prep(
    const float* __restrict__ We, const float* __restrict__ be,
    const float* __restrict__ Wm1, const float* __restrict__ bm1,
    const float* __restrict__ Wm2, const float* __restrict__ bm2,
    const float* __restrict__ Wu1,
    float* __restrict__ We2, float* __restrict__ bp,
    float* __restrict__ Wma, float* __restrict__ bma)
{
    const int tid = threadIdx.x;
    const int j = tid & (H - 1);
    const int q = tid >> 6;
    if (q == 0) {
        float s0 = 0.f, s1 = 0.f, sb = 0.f;
        for (int k = 0; k < H; ++k) {
            const float w = Wm1[(2 * H + k) * H + j];
            s0 = fmaf(We[k], w, s0);
            s1 = fmaf(We[H + k], w, s1);
            sb = fmaf(be[k], w, sb);
        }
        We2[j]     = s0;
        We2[H + j] = s1;
        bp[j]      = sb + bm1[j];
        float sm = 0.f;
        for (int l = 0; l < H; ++l)
            sm = fmaf(bm2[l], Wu1[(H + l) * H + j], sm);
        bma[j] = sm;
    }
    for (int k = q * (H / 4); k < (q + 1) * (H / 4); ++k) {
        float s = 0.f;
        for (int l = 0; l < H; ++l)
            s = fmaf(Wm2[k * H + l], Wu1[(H + l) * H + j], s);
        Wma[k * H + j] = s;
    }
}

// ---------------------------------------------------------------------------
// k1_mfma: encoder + 4 projections on matrix cores. A now stored bf16.
// ---------------------------------------------------------------------------
__global__ __launch_bounds__(256) void k1_mfma(
    const float* __restrict__ x,
    const float* __restrict__ Wn1, const float* __restrict__ bn1,
    const float* __restrict__ Wn2, const float* __restrict__ bn2,
    const float* __restrict__ Wm1, const float* __restrict__ Wu1,
    unsigned short* __restrict__ Ab, unsigned short* __restrict__ Bb,
    unsigned short* __restrict__ HUb)
{
    __shared__ unsigned short hbuf[4][16 * 64];
    __shared__ bf16x8 wfrag[4][4][2][64];

    const int tid = threadIdx.x;
    const int w   = tid >> 6;
    const int l   = tid & 63;
    const int l15 = l & 15;
    const int lb  = l >> 4;

    const float* Wmats[4] = { Wn2, Wm1, Wm1 + H * H, Wu1 };
    const float* Wsrc = Wmats[w];
#pragma unroll
    for (int t = 0; t < 4; ++t)
#pragma unroll
        for (int kh = 0; kh < 2; ++kh) {
            bf16x8 f;
#pragma unroll
            for (int j = 0; j < 8; ++j) {
                const int k = kh * 32 + lb * 8 + j;
                f[j] = (short)f2bf(Wsrc[k * H + 16 * t + l15]);
            }
            wfrag[w][t][kh][l] = f;
        }

    bf16x8 b1frag[4];
    float bn1t[4], bn2t[4];
#pragma unroll
    for (int t = 0; t < 4; ++t) {
        bn1t[t] = bn1[16 * t + l15];
        bn2t[t] = bn2[16 * t + l15];
#pragma unroll
        for (int j = 0; j < 8; ++j) {
            float v = (lb == 0 && j < 5) ? Wn1[j * H + 16 * t + l15] : 0.f;
            b1frag[t][j] = (short)f2bf(v);
        }
    }
    __syncthreads();

    const int g = blockIdx.x * 4 + w;
    if (g * 16 >= NN) return;
    const int n0 = g * 16;
    const f32x4 z4 = {0.f, 0.f, 0.f, 0.f};

    bf16x8 xf = {0, 0, 0, 0, 0, 0, 0, 0};
    if (lb == 0) {
        const float* xr = x + (size_t)(n0 + l15) * 5;
#pragma unroll
        for (int j = 0; j < 5; ++j) xf[j] = (short)f2bf(xr[j]);
    }
    f32x4 acc1[4];
#pragma unroll
    for (int t = 0; t < 4; ++t)
        acc1[t] = __builtin_amdgcn_mfma_f32_16x16x32_bf16(xf, b1frag[t], z4, 0, 0, 0);
#pragma unroll
    for (int t = 0; t < 4; ++t)
#pragma unroll
        for (int q = 0; q < 4; ++q) {
            const int m = lb * 4 + q;
            const int idx = (m * 64 + 16 * t + l15) ^ ((m & 7) << 3);
            hbuf[w][idx] = f2bf(fmaxf(acc1[t][q] + bn1t[t], 0.f));
        }
    __builtin_amdgcn_wave_barrier();

    auto rdA = [&](int kh) {
        const int idx = (l15 * 64 + kh * 32 + lb * 8) ^ ((l15 & 7) << 3);
        return *reinterpret_cast<const bf16x8*>(&hbuf[w][idx]);
    };

    {
        bf16x8 a0 = rdA(0), a1 = rdA(1);
        __builtin_amdgcn_wave_barrier();
        f32x4 acc[4];
#pragma unroll
        for (int t = 0; t < 4; ++t) {
            acc[t] = __builtin_amdgcn_mfma_f32_16x16x32_bf16(a0, wfrag[0][t][0][l], z4, 0, 0, 0);
            acc[t] = __builtin_amdgcn_mfma_f32_16x16x32_bf16(a1, wfrag[0][t][1][l], acc[t], 0, 0, 0);
        }
#pragma unroll
        for (int t = 0; t < 4; ++t)
#pragma unroll
            for (int q = 0; q < 4; ++q) {
                const int m = lb * 4 + q;
                const int idx = (m * 64 + 16 * t + l15) ^ ((m & 7) << 3);
                hbuf[w][idx] = f2bf(acc[t][q] + bn2t[t]);
            }
        __builtin_amdgcn_wave_barrier();
    }

    bf16x8 h0 = rdA(0), h1v = rdA(1);
#pragma unroll
    for (int t = 0; t < 4; ++t) {
        f32x4 acc = __builtin_amdgcn_mfma_f32_16x16x32_bf16(h0, wfrag[1][t][0][l], z4, 0, 0, 0);
        acc = __builtin_amdgcn_mfma_f32_16x16x32_bf16(h1v, wfrag[1][t][1][l], acc, 0, 0, 0);
#pragma unroll
        for (int q = 0; q < 4; ++q)
            Ab[(size_t)(n0 + lb * 4 + q) * H + 16 * t + l15] = f2bf(acc[q]);
    }
#pragma unroll
    for (int t = 0; t < 4; ++t) {
        f32x4 acc = __builtin_amdgcn_mfma_f32_16x16x32_bf16(h0, wfrag[2][t][0][l], z4, 0, 0, 0);
        acc = __builtin_amdgcn_mfma_f32_16x16x32_bf16(h1v, wfrag[2][t][1][l], acc, 0, 0, 0);
#pragma unroll
        for (int q = 0; q < 4; ++q)
            Bb[(size_t)(n0 + lb * 4 + q) * H + 16 * t + l15] = f2bf(acc[q]);
    }
#pragma unroll
    for (int t = 0; t < 4; ++t) {
        f32x4 acc = __builtin_amdgcn_mfma_f32_16x16x32_bf16(h0, wfrag[3][t][0][l], z4, 0, 0, 0);
        acc = __builtin_amdgcn_mfma_f32_16x16x32_bf16(h1v, wfrag[3][t][1][l], acc, 0, 0, 0);
#pragma unroll
        for (int q = 0; q < 4; ++q)
            HUb[(size_t)(n0 + lb * 4 + q) * H + 16 * t + l15] = f2bf(acc[q]);
    }
}

// ---------------------------------------------------------------------------
// k2h0: coarse-bucket histogram (LDS-aggregated)
// ---------------------------------------------------------------------------
__global__ __launch_bounds__(256) void k2h0(
    const int* __restrict__ eidx, int* __restrict__ gbcnt)
{
    __shared__ int hl[NBUCK];
    const int tid = threadIdx.x;
    for (int i = tid; i < NBUCK; i += 256) hl[i] = 0;
    __syncthreads();
    const int stride = gridDim.x * 256;
    for (int e = blockIdx.x * 256 + tid; e < NE; e += stride)
        atomicAdd(&hl[eidx[NE + e] >> 8], 1);
    __syncthreads();
    for (int i = tid; i < NBUCK; i += 256)
        if (hl[i]) atomicAdd(&gbcnt[i], hl[i]);
}

// ---------------------------------------------------------------------------
// k2h1: single-block scan of bucket counts -> bbase[NBUCK+1], gcur[]
// ---------------------------------------------------------------------------
__global__ __launch_bounds__(256) void k2h1(
    const int* __restrict__ gbcnt, int* __restrict__ bbase, int* __restrict__ gcur)
{
    __shared__ int wsum[4];
    const int tid = threadIdx.x, lane = tid & 63, wv = tid >> 6;
    const int v = (tid < NBUCK) ? gbcnt[tid] : 0;
    int s = v;
#pragma unroll
    for (int d = 1; d < 64; d <<= 1) {
        int t = __shfl_up(s, (unsigned)d, 64);
        if (lane >= d) s += t;
    }
    if (lane == 63) wsum[wv] = s;
    __syncthreads();
    int wb = 0;
#pragma unroll
    for (int k = 0; k < 4; ++k) wb += (k < wv) ? wsum[k] : 0;
    const int excl = wb + s - v;
    if (tid < NBUCK) {
        bbase[tid] = excl;
        gcur[tid]  = excl;
        if (tid == NBUCK - 1) bbase[NBUCK] = excl + v;
    }
}

// ---------------------------------------------------------------------------
// k2s: chunk counting-sort into bucket-sorted rec (sequential flush runs)
// ---------------------------------------------------------------------------
__global__ __launch_bounds__(256) void k2s_sort(
    const int* __restrict__ eidx, const float* __restrict__ ea,
    int* __restrict__ gcur, uint2* __restrict__ rec)
{
    __shared__ int hcnt[256], delta[256], c2[256];
    __shared__ int wsum[4];
    __shared__ uint2 srt[CHUNK];
    const int tid = threadIdx.x, lane = tid & 63, wv = tid >> 6;
    const int cbase = blockIdx.x * CHUNK;
    const int nck = (NE - cbase < CHUNK) ? (NE - cbase) : CHUNK;

    hcnt[tid] = 0;
    __syncthreads();

    unsigned rx[16], ry[16];
#pragma unroll
    for (int k = 0; k < 16; ++k) {
        const int i = k * 256 + tid;
        if (i < nck) {
            const int e = cbase + i;
            const int dst = eidx[NE + e];
            const int src = eidx[e];
            const float2 q = ((const float2*)ea)[e];
            rx[k] = (unsigned)src | ((unsigned)(dst & 255) << 16)
                  | ((unsigned)(dst >> 8) << 24);
            ry[k] = (unsigned)f2bf(q.x) | ((unsigned)f2bf(q.y) << 16);
            atomicAdd(&hcnt[dst >> 8], 1);
        } else rx[k] = 0xFFFFFFFFu;
    }
    __syncthreads();

    const int v = hcnt[tid];
    int s = v;
#pragma unroll
    for (int d = 1; d < 64; d <<= 1) {
        int t = __shfl_up(s, (unsigned)d, 64);
        if (lane >= d) s += t;
    }
    if (lane == 63) wsum[wv] = s;
    __syncthreads();
    int wb = 0;
#pragma unroll
    for (int k = 0; k < 4; ++k) wb += (k < wv) ? wsum[k] : 0;
    const int excl = wb + s - v;
    c2[tid] = excl;
    if (tid < NBUCK) {
        const int base = v ? atomicAdd(&gcur[tid], v) : 0;
        delta[tid] = base - excl;
    }
    __syncthreads();

#pragma unroll
    for (int k = 0; k < 16; ++k) {
        if (rx[k] != 0xFFFFFFFFu) {
            const int b = rx[k] >> 24;
            const int slot = atomicAdd(&c2[b], 1);
            srt[slot] = (uint2){rx[k], ry[k]};
        }
    }
    __syncthreads();

    for (int i = tid; i < nck; i += 256) {
        const uint2 rr = srt[i];
        rec[i + delta[rr.x >> 24]] = rr;
    }
}

// ---------------------------------------------------------------------------
// k2d: per-coarse-bucket exact CSR (off + node-sorted rec2)
// ---------------------------------------------------------------------------
__global__ __launch_bounds__(256) void k2d_csr(
    const int* __restrict__ bbase, const uint2* __restrict__ rec,
    int* __restrict__ off, uint2* __restrict__ rec2)
{
    __shared__ int hl[256], c2[256];
    __shared__ int wsum[4];
    const int tid = threadIdx.x, lane = tid & 63, wv = tid >> 6;
    const int b = blockIdx.x;
    const int r0 = bbase[b], r1 = bbase[b + 1];
    const int nr = r1 - r0;

    hl[tid] = 0;
    __syncthreads();
    for (int i = tid; i < nr; i += 256)
        atomicAdd(&hl[(rec[r0 + i].x >> 16) & 255], 1);
    __syncthreads();

    const int v = hl[tid];
    int s = v;
#pragma unroll
    for (int d = 1; d < 64; d <<= 1) {
        int t = __shfl_up(s, (unsigned)d, 64);
        if (lane >= d) s += t;
    }
    if (lane == 63) wsum[wv] = s;
    __syncthreads();
    int wb = 0;
#pragma unroll
    for (int k = 0; k < 4; ++k) wb += (k < wv) ? wsum[k] : 0;
    const int excl = wb + s - v;
    c2[tid] = r0 + excl;
    const int n = b * 256 + tid;
    if (n < NN) off[n] = r0 + excl;
    if (b == NBUCK - 1 && tid == 0) off[NN] = NE;
    __syncthreads();

    for (int i = tid; i < nr; i += 256) {
        const uint2 rr = rec[r0 + i];
        const int ln = (rr.x >> 16) & 255;
        const int pos = atomicAdd(&c2[ln], 1);
        rec2[pos] = (uint2){rr.x & 0xFFFFu, rr.y};
    }
}

// ---------------------------------------------------------------------------
// k3r: PURE aggregation. One wave per node, zero LDS, max occupancy.
//   Rb[n] = bf16( sum_e relu(Ab[n] + Bb[src] + ea*We2 + bp) )
// ---------------------------------------------------------------------------
__global__ __launch_bounds__(256, 8) void k3r_agg(
    const int* __restrict__ off, const uint2* __restrict__ rec2,
    const unsigned short* __restrict__ Ab, const unsigned short* __restrict__ Bb,
    const float* __restrict__ We2, const float* __restrict__ bp,
    unsigned short* __restrict__ Rb)
{
    const int j = threadIdx.x & 63;
    const int wid = (blockIdx.x * 256 + threadIdx.x) >> 6;
    const int nw = (gridDim.x * 256) >> 6;
    const float w0 = We2[j], w1 = We2[H + j], bpj = bp[j];

    for (int n = wid; n < NN; n += nw) {
        const int e0 = __builtin_amdgcn_readfirstlane(off[n]);
        const int e1 = __builtin_amdgcn_readfirstlane(off[n + 1]);
        const float a = bf2f(Ab[(size_t)n * H + j]) + bpj;
        float rsum = 0.f;

        auto proc = [&](unsigned rx, unsigned ry) {
            const float bb = bf2f(Bb[(size_t)(rx & 0xFFFFu) * H + j]);
            float z = a + bb;
            z = fmaf(__uint_as_float(ry << 16), w0, z);
            z = fmaf(__uint_as_float(ry & 0xFFFF0000u), w1, z);
            rsum += fmaxf(z, 0.f);
        };

        int e = e0;
        if ((e & 1) && e < e1) {              // align to uint4
            const uint2 r = rec2[e];
            proc(r.x, r.y);
            ++e;
        }
        for (; e + 8 <= e1; e += 8) {         // 4x uint4 = 8 records in flight
            const uint4 p0 = *(const uint4*)(rec2 + e);
            const uint4 p1 = *(const uint4*)(rec2 + e + 2);
            const uint4 p2 = *(const uint4*)(rec2 + e + 4);
            const uint4 p3 = *(const uint4*)(rec2 + e + 6);
            proc(p0.x, p0.y); proc(p0.z, p0.w);
            proc(p1.x, p1.y); proc(p1.z, p1.w);
            proc(p2.x, p2.y); proc(p2.z, p2.w);
            proc(p3.x, p3.y); proc(p3.z, p3.w);
        }
        for (; e + 2 <= e1; e += 2) {
            const uint4 p0 = *(const uint4*)(rec2 + e);
            proc(p0.x, p0.y); proc(p0.z, p0.w);
        }
        if (e < e1) {
            const uint2 r = rec2[e];
            proc(r.x, r.y);
        }
        Rb[(size_t)n * H + j] = f2bf(rsum);
    }
}

// ---------------------------------------------------------------------------
// k4_mfma: update MLP on matrix cores, 16-node tiles.
//   s = R@Wma ; z = relu(HU + (s + c*bma)/max(c,1) + bu1) ; out = z@Wu2 + bu2
// ---------------------------------------------------------------------------
__global__ __launch_bounds__(256) void k4_mfma(
    const int* __restrict__ off,
    const unsigned short* __restrict__ Rb, const unsigned short* __restrict__ HUb,
    const float* __restrict__ Wma, const float* __restrict__ bma,
    const float* __restrict__ bu1,
    const float* __restrict__ Wu2, const float* __restrict__ bu2,
    float* __restrict__ out)
{
    __shared__ unsigned short hbuf[4][16 * 64];   // 8 KB
    __shared__ bf16x8 wfrag[2][4][2][64];         // 16 KB

    const int tid = threadIdx.x;
    const int w   = tid >> 6;
    const int l   = tid & 63;
    const int l15 = l & 15;
    const int lb  = l >> 4;

    if (w < 2) {
        const float* Wsrc = (w == 0) ? Wma : Wu2;
#pragma unroll
        for (int t = 0; t < 4; ++t)
#pragma unroll
            for (int kh = 0; kh < 2; ++kh) {
                bf16x8 f;
#pragma unroll
                for (int j = 0; j < 8; ++j) {
                    const int k = kh * 32 + lb * 8 + j;
                    f[j] = (short)f2bf(Wsrc[k * H + 16 * t + l15]);
                }
                wfrag[w][t][kh][l] = f;
            }
    }
    __syncthreads();

    const int g = blockIdx.x * 4 + w;
    if (g * 16 >= NN) return;
    const int n0 = g * 16;
    const f32x4 z4 = {0.f, 0.f, 0.f, 0.f};

    // R A-fragments (direct bf16 loads)
    const bf16x8 r0 = *(const bf16x8*)(Rb + (size_t)(n0 + l15) * H + lb * 8);
    const bf16x8 r1 = *(const bf16x8*)(Rb + (size_t)(n0 + l15) * H + 32 + lb * 8);

    // per-row edge count (lanes 0..15 hold rows 0..15)
    const float cntv = (float)(off[n0 + l15 + 1] - off[n0 + l15]);

    float bmat[4], bu1t[4], bu2t[4];
#pragma unroll
    for (int t = 0; t < 4; ++t) {
        bmat[t] = bma[16 * t + l15];
        bu1t[t] = bu1[16 * t + l15];
        bu2t[t] = bu2[16 * t + l15];
    }

    // s = R @ Wma  -> epilogue -> z (bf16, swizzled hbuf)
#pragma unroll
    for (int t = 0; t < 4; ++t) {
        f32x4 acc = __builtin_amdgcn_mfma_f32_16x16x32_bf16(r0, wfrag[0][t][0][l], z4, 0, 0, 0);
        acc = __builtin_amdgcn_mfma_f32_16x16x32_bf16(r1, wfrag[0][t][1][l], acc, 0, 0, 0);
#pragma unroll
        for (int q = 0; q < 4; ++q) {
            const int row = lb * 4 + q;
            const float c  = __shfl(cntv, row, 64);
            const float cc = fmaxf(c, 1.0f);
            const float hu = bf2f(HUb[(size_t)(n0 + row) * H + 16 * t + l15]);
            float z = hu + fmaf(c, bmat[t], acc[q]) / cc + bu1t[t];
            z = fmaxf(z, 0.f);
            const int idx = (row * 64 + 16 * t + l15) ^ ((row & 7) << 3);
            hbuf[w][idx] = f2bf(z);
        }
    }
    __builtin_amdgcn_wave_barrier();

    const int ia0 = (l15 * 64 + 0  + lb * 8) ^ ((l15 & 7) << 3);
    const int ia1 = (l15 * 64 + 32 + lb * 8) ^ ((l15 & 7) << 3);
    const bf16x8 a0 = *reinterpret_cast<const bf16x8*>(&hbuf[w][ia0]);
    const bf16x8 a1 = *reinterpret_cast<const bf16x8*>(&hbuf[w][ia1]);

#pragma unroll
    for (int t = 0; t < 4; ++t) {
        f32x4 acc = __builtin_amdgcn_mfma_f32_16x16x32_bf16(a0, wfrag[1][t][0][l], z4, 0, 0, 0);
        acc = __builtin_amdgcn_mfma_f32_16x16x32_bf16(a1, wfrag[1][t][1][l], acc, 0, 0, 0);
#pragma unroll
        for (int q = 0; q < 4; ++q)
            out[(size_t)(n0 + lb * 4 + q) * H + 16 * t + l15] = acc[q] + bu2t[t];
    }
}

// ---------------------------------------------------------------------------
extern "C" void kernel_launch(void* const* d_in, const int* in_sizes, int n_in,
                              void* d_out, int out_size, void* d_ws, size_t ws_size,
                              hipStream_t stream) {
    (void)in_sizes; (void)n_in; (void)out_size; (void)ws_size;
    const float* x    = (const float*)d_in[0];
    const float* eatt = (const float*)d_in[1];
    const int*   eidx = (const int*)d_in[2];
    const float* Wn1  = (const float*)d_in[3];
    const float* bn1  = (const float*)d_in[4];
    const float* Wn2  = (const float*)d_in[5];
    const float* bn2  = (const float*)d_in[6];
    const float* We   = (const float*)d_in[7];
    const float* be   = (const float*)d_in[8];
    const float* Wm1  = (const float*)d_in[9];
    const float* bm1  = (const float*)d_in[10];
    const float* Wm2  = (const float*)d_in[11];
    const float* bm2  = (const float*)d_in[12];
    const float* Wu1  = (const float*)d_in[13];
    const float* bu1  = (const float*)d_in[14];
    const float* Wu2  = (const float*)d_in[15];
    const float* bu2  = (const float*)d_in[16];
    float* out = (float*)d_out;

    char* wsb = (char*)d_ws;
    unsigned short* Ab  = (unsigned short*)wsb;                    // NN*H bf16
    unsigned short* Bb  = Ab + (size_t)NN * H;                     // NN*H bf16
    unsigned short* HUb = Bb + (size_t)NN * H;                     // NN*H bf16
    unsigned short* Rb  = HUb + (size_t)NN * H;                    // NN*H bf16
    uint2* rec  = (uint2*)(Rb + (size_t)NN * H);                   // NE*8B
    uint2* rec2 = rec + NE;                                        // NE*8B
    int*   off  = (int*)(rec2 + NE);                               // NN+1
    int*   bbase= off + NN + 1;                                    // NBUCK+1
    int*   gbcnt= bbase + NBUCK + 1;                               // NBUCK
    int*   gcur = gbcnt + NBUCK;                                   // NBUCK
    float* We2  = (float*)(gcur + NBUCK);                          // 2*H
    float* bp   = We2 + 2 * H;                                     // H
    float* Wma  = bp + H;                                          // H*H
    float* bma  = Wma + H * H;                                     // H

    hipMemsetAsync(gbcnt, 0, NBUCK * sizeof(int), stream);

    k0_prep<<<1, 256, 0, stream>>>(We, be, Wm1, bm1, Wm2, bm2, Wu1,
                                   We2, bp, Wma, bma);
    k1_mfma<<<(NN / 16 + 3) / 4, 256, 0, stream>>>(x, Wn1, bn1, Wn2, bn2,
                                                   Wm1, Wu1, Ab, Bb, HUb);
    k2h0<<<1024, 256, 0, stream>>>(eidx, gbcnt);
    k2h1<<<1, 256, 0, stream>>>(gbcnt, bbase, gcur);
    k2s_sort<<<NCHUNK, 256, 0, stream>>>(eidx, eatt, gcur, rec);
    k2d_csr<<<NBUCK, 256, 0, stream>>>(bbase, rec, off, rec2);
    k3r_agg<<<2048, 256, 0, stream>>>(off, rec2, Ab, Bb, We2, bp, Rb);
    k4_mfma<<<(NN / 16 + 3) / 4, 256, 0, stream>>>(off, Rb, HUb, Wma, bma,
                                                   bu1, Wu2, bu2, out);
}

// Round 11
// 218.940 us; speedup vs baseline: 2.7524x; 1.1433x over previous
//
#include <hip/hip_runtime.h>
#include <hip/hip_bf16.h>

#define NN 50000
#define NE 1200000
#define H 64
#define NBUCK 196          // coarse buckets of 256 nodes (dst>>8)
#define CHUNK 4096
#define NCHUNK ((NE + CHUNK - 1) / CHUNK)   // 293
#define K1B 782            // k1 blocks (ceil(3125 groups / 4 waves))
#define HISTB 256          // histogram blocks appended to k1 grid
#define MAXB 7000          // per-bucket record capacity in k2d LDS (mean 6122, +11 sigma)

using bf16x8 = __attribute__((ext_vector_type(8))) short;
using f32x4  = __attribute__((ext_vector_type(4))) float;

static __device__ __forceinline__ unsigned short f2bf(float f) {
    __hip_bfloat16 h = __float2bfloat16(f);
    return *reinterpret_cast<unsigned short*>(&h);
}
static __device__ __forceinline__ float bf2f(unsigned short u) {
    return __uint_as_float((unsigned)u << 16);
}

// ---------------------------------------------------------------------------
// kA: fused  [blocks 0..K1B-1]  node encoder + 4 projections (MFMA)
//            [blocks K1B..K1B+HISTB-1]  coarse-bucket histogram of dst
// ---------------------------------------------------------------------------
__global__ __launch_bounds__(256) void kA_node_hist(
    const float* __restrict__ x,
    const float* __restrict__ Wn1, const float* __restrict__ bn1,
    const float* __restrict__ Wn2, const float* __restrict__ bn2,
    const float* __restrict__ Wm1, const float* __restrict__ Wu1,
    const int* __restrict__ eidx,
    unsigned short* __restrict__ Ab, unsigned short* __restrict__ Bb,
    unsigned short* __restrict__ HUb, int* __restrict__ gbcnt)
{
    __shared__ unsigned short hbuf[4][16 * 64];   // 8 KB (hist part reuses as int[NBUCK])
    __shared__ bf16x8 wfrag[4][4][2][64];         // 32 KB

    const int tid = threadIdx.x;

    if (blockIdx.x >= K1B) {
        // ---- histogram part ----
        int* hl = (int*)&hbuf[0][0];
        for (int i = tid; i < NBUCK; i += 256) hl[i] = 0;
        __syncthreads();
        const int hb = blockIdx.x - K1B;
        const int stride = HISTB * 256;
        for (int e = hb * 256 + tid; e < NE; e += stride)
            atomicAdd(&hl[eidx[NE + e] >> 8], 1);
        __syncthreads();
        for (int i = tid; i < NBUCK; i += 256)
            if (hl[i]) atomicAdd(&gbcnt[i], hl[i]);
        return;
    }

    // ---- node encoder part ----
    const int w   = tid >> 6;
    const int l   = tid & 63;
    const int l15 = l & 15;
    const int lb  = l >> 4;

    const float* Wmats[4] = { Wn2, Wm1, Wm1 + H * H, Wu1 };
    const float* Wsrc = Wmats[w];
#pragma unroll
    for (int t = 0; t < 4; ++t)
#pragma unroll
        for (int kh = 0; kh < 2; ++kh) {
            bf16x8 f;
#pragma unroll
            for (int j = 0; j < 8; ++j) {
                const int k = kh * 32 + lb * 8 + j;
                f[j] = (short)f2bf(Wsrc[k * H + 16 * t + l15]);
            }
            wfrag[w][t][kh][l] = f;
        }

    bf16x8 b1frag[4];
    float bn1t[4], bn2t[4];
#pragma unroll
    for (int t = 0; t < 4; ++t) {
        bn1t[t] = bn1[16 * t + l15];
        bn2t[t] = bn2[16 * t + l15];
#pragma unroll
        for (int j = 0; j < 8; ++j) {
            float v = (lb == 0 && j < 5) ? Wn1[j * H + 16 * t + l15] : 0.f;
            b1frag[t][j] = (short)f2bf(v);
        }
    }
    __syncthreads();

    const int g = blockIdx.x * 4 + w;
    if (g * 16 >= NN) return;
    const int n0 = g * 16;
    const f32x4 z4 = {0.f, 0.f, 0.f, 0.f};

    bf16x8 xf = {0, 0, 0, 0, 0, 0, 0, 0};
    if (lb == 0) {
        const float* xr = x + (size_t)(n0 + l15) * 5;
#pragma unroll
        for (int j = 0; j < 5; ++j) xf[j] = (short)f2bf(xr[j]);
    }
    f32x4 acc1[4];
#pragma unroll
    for (int t = 0; t < 4; ++t)
        acc1[t] = __builtin_amdgcn_mfma_f32_16x16x32_bf16(xf, b1frag[t], z4, 0, 0, 0);
#pragma unroll
    for (int t = 0; t < 4; ++t)
#pragma unroll
        for (int q = 0; q < 4; ++q) {
            const int m = lb * 4 + q;
            const int idx = (m * 64 + 16 * t + l15) ^ ((m & 7) << 3);
            hbuf[w][idx] = f2bf(fmaxf(acc1[t][q] + bn1t[t], 0.f));
        }
    __builtin_amdgcn_wave_barrier();

    auto rdA = [&](int kh) {
        const int idx = (l15 * 64 + kh * 32 + lb * 8) ^ ((l15 & 7) << 3);
        return *reinterpret_cast<const bf16x8*>(&hbuf[w][idx]);
    };

    {
        bf16x8 a0 = rdA(0), a1 = rdA(1);
        __builtin_amdgcn_wave_barrier();
        f32x4 acc[4];
#pragma unroll
        for (int t = 0; t < 4; ++t) {
            acc[t] = __builtin_amdgcn_mfma_f32_16x16x32_bf16(a0, wfrag[0][t][0][l], z4, 0, 0, 0);
            acc[t] = __builtin_amdgcn_mfma_f32_16x16x32_bf16(a1, wfrag[0][t][1][l], acc[t], 0, 0, 0);
        }
#pragma unroll
        for (int t = 0; t < 4; ++t)
#pragma unroll
            for (int q = 0; q < 4; ++q) {
                const int m = lb * 4 + q;
                const int idx = (m * 64 + 16 * t + l15) ^ ((m & 7) << 3);
                hbuf[w][idx] = f2bf(acc[t][q] + bn2t[t]);
            }
        __builtin_amdgcn_wave_barrier();
    }

    bf16x8 h0 = rdA(0), h1v = rdA(1);
#pragma unroll
    for (int t = 0; t < 4; ++t) {
        f32x4 acc = __builtin_amdgcn_mfma_f32_16x16x32_bf16(h0, wfrag[1][t][0][l], z4, 0, 0, 0);
        acc = __builtin_amdgcn_mfma_f32_16x16x32_bf16(h1v, wfrag[1][t][1][l], acc, 0, 0, 0);
#pragma unroll
        for (int q = 0; q < 4; ++q)
            Ab[(size_t)(n0 + lb * 4 + q) * H + 16 * t + l15] = f2bf(acc[q]);
    }
#pragma unroll
    for (int t = 0; t < 4; ++t) {
        f32x4 acc = __builtin_amdgcn_mfma_f32_16x16x32_bf16(h0, wfrag[2][t][0][l], z4, 0, 0, 0);
        acc = __builtin_amdgcn_mfma_f32_16x16x32_bf16(h1v, wfrag[2][t][1][l], acc, 0, 0, 0);
#pragma unroll
        for (int q = 0; q < 4; ++q)
            Bb[(size_t)(n0 + lb * 4 + q) * H + 16 * t + l15] = f2bf(acc[q]);
    }
#pragma unroll
    for (int t = 0; t < 4; ++t) {
        f32x4 acc = __builtin_amdgcn_mfma_f32_16x16x32_bf16(h0, wfrag[3][t][0][l], z4, 0, 0, 0);
        acc = __builtin_amdgcn_mfma_f32_16x16x32_bf16(h1v, wfrag[3][t][1][l], acc, 0, 0, 0);
#pragma unroll
        for (int q = 0; q < 4; ++q)
            HUb[(size_t)(n0 + lb * 4 + q) * H + 16 * t + l15] = f2bf(acc[q]);
    }
}

// ---------------------------------------------------------------------------
// kB: fused  single-block scan of bucket counts -> bbase/gcur  +  k0 weight
//     folding (We2, bp, Wma, bma). Independent phases, one launch.
// ---------------------------------------------------------------------------
__global__ __launch_bounds__(256) void kB_scan_prep(
    const int* __restrict__ gbcnt, int* __restrict__ bbase, int* __restrict__ gcur,
    const float* __restrict__ We, const float* __restrict__ be,
    const float* __restrict__ Wm1, const float* __restrict__ bm1,
    const float* __restrict__ Wm2, const float* __restrict__ bm2,
    const float* __restrict__ Wu1,
    float* __restrict__ We2, float* __restrict__ bp,
    float* __restrict__ Wma, float* __restrict__ bma)
{
    __shared__ int wsum[4];
    const int tid = threadIdx.x, lane = tid & 63, wv = tid >> 6;

    // ---- scan part ----
    const int v = (tid < NBUCK) ? gbcnt[tid] : 0;
    int s = v;
#pragma unroll
    for (int d = 1; d < 64; d <<= 1) {
        int t = __shfl_up(s, (unsigned)d, 64);
        if (lane >= d) s += t;
    }
    if (lane == 63) wsum[wv] = s;
    __syncthreads();
    int wb = 0;
#pragma unroll
    for (int k = 0; k < 4; ++k) wb += (k < wv) ? wsum[k] : 0;
    const int excl = wb + s - v;
    if (tid < NBUCK) {
        bbase[tid] = excl;
        gcur[tid]  = excl;
        if (tid == NBUCK - 1) bbase[NBUCK] = excl + v;
    }

    // ---- prep part (k0) ----
    const int j = tid & (H - 1);
    const int q = tid >> 6;
    if (q == 0) {
        float s0 = 0.f, s1 = 0.f, sb = 0.f;
        for (int k = 0; k < H; ++k) {
            const float w = Wm1[(2 * H + k) * H + j];
            s0 = fmaf(We[k], w, s0);
            s1 = fmaf(We[H + k], w, s1);
            sb = fmaf(be[k], w, sb);
        }
        We2[j]     = s0;
        We2[H + j] = s1;
        bp[j]      = sb + bm1[j];
        float sm = 0.f;
        for (int l = 0; l < H; ++l)
            sm = fmaf(bm2[l], Wu1[(H + l) * H + j], sm);
        bma[j] = sm;
    }
    for (int k = q * (H / 4); k < (q + 1) * (H / 4); ++k) {
        float s2 = 0.f;
        for (int l = 0; l < H; ++l)
            s2 = fmaf(Wm2[k * H + l], Wu1[(H + l) * H + j], s2);
        Wma[k * H + j] = s2;
    }
}

// ---------------------------------------------------------------------------
// k2s: chunk counting-sort into bucket-sorted rec (sequential flush runs)
// ---------------------------------------------------------------------------
__global__ __launch_bounds__(256) void k2s_sort(
    const int* __restrict__ eidx, const float* __restrict__ ea,
    int* __restrict__ gcur, uint2* __restrict__ rec)
{
    __shared__ int hcnt[256], delta[256], c2[256];
    __shared__ int wsum[4];
    __shared__ uint2 srt[CHUNK];
    const int tid = threadIdx.x, lane = tid & 63, wv = tid >> 6;
    const int cbase = blockIdx.x * CHUNK;
    const int nck = (NE - cbase < CHUNK) ? (NE - cbase) : CHUNK;

    hcnt[tid] = 0;
    __syncthreads();

    unsigned rx[16], ry[16];
#pragma unroll
    for (int k = 0; k < 16; ++k) {
        const int i = k * 256 + tid;
        if (i < nck) {
            const int e = cbase + i;
            const int dst = eidx[NE + e];
            const int src = eidx[e];
            const float2 q = ((const float2*)ea)[e];
            rx[k] = (unsigned)src | ((unsigned)(dst & 255) << 16)
                  | ((unsigned)(dst >> 8) << 24);
            ry[k] = (unsigned)f2bf(q.x) | ((unsigned)f2bf(q.y) << 16);
            atomicAdd(&hcnt[dst >> 8], 1);
        } else rx[k] = 0xFFFFFFFFu;
    }
    __syncthreads();

    const int v = hcnt[tid];
    int s = v;
#pragma unroll
    for (int d = 1; d < 64; d <<= 1) {
        int t = __shfl_up(s, (unsigned)d, 64);
        if (lane >= d) s += t;
    }
    if (lane == 63) wsum[wv] = s;
    __syncthreads();
    int wb = 0;
#pragma unroll
    for (int k = 0; k < 4; ++k) wb += (k < wv) ? wsum[k] : 0;
    const int excl = wb + s - v;
    c2[tid] = excl;
    if (tid < NBUCK) {
        const int base = v ? atomicAdd(&gcur[tid], v) : 0;
        delta[tid] = base - excl;
    }
    __syncthreads();

#pragma unroll
    for (int k = 0; k < 16; ++k) {
        if (rx[k] != 0xFFFFFFFFu) {
            const int b = rx[k] >> 24;
            const int slot = atomicAdd(&c2[b], 1);
            srt[slot] = (uint2){rx[k], ry[k]};
        }
    }
    __syncthreads();

    for (int i = tid; i < nck; i += 256) {
        const uint2 rr = srt[i];
        rec[i + delta[rr.x >> 24]] = rr;
    }
}

// ---------------------------------------------------------------------------
// k2d: per-coarse-bucket exact CSR with LDS-staged output: hist pass (read),
// LDS scan -> off[], scatter pass into LDS srt, LINEAR coalesced flush.
// rec2: { src , bf16 ea pair }
// ---------------------------------------------------------------------------
__global__ __launch_bounds__(256) void k2d_csr(
    const int* __restrict__ bbase, const uint2* __restrict__ rec,
    int* __restrict__ off, uint2* __restrict__ rec2)
{
    __shared__ int hl[256];
    __shared__ int cur[256];
    __shared__ int wsum[4];
    __shared__ uint2 srt[MAXB];     // 56 KB
    const int tid = threadIdx.x, lane = tid & 63, wv = tid >> 6;
    const int b = blockIdx.x;
    const int r0 = bbase[b], r1 = bbase[b + 1];
    const int nr = r1 - r0;

    hl[tid] = 0;
    __syncthreads();
    for (int i = tid; i < nr; i += 256)
        atomicAdd(&hl[(rec[r0 + i].x >> 16) & 255], 1);
    __syncthreads();

    const int v = hl[tid];
    int s = v;
#pragma unroll
    for (int d = 1; d < 64; d <<= 1) {
        int t = __shfl_up(s, (unsigned)d, 64);
        if (lane >= d) s += t;
    }
    if (lane == 63) wsum[wv] = s;
    __syncthreads();
    int wb = 0;
#pragma unroll
    for (int k = 0; k < 4; ++k) wb += (k < wv) ? wsum[k] : 0;
    const int excl = wb + s - v;
    cur[tid] = excl;                        // bucket-local base
    const int n = b * 256 + tid;
    if (n < NN) off[n] = r0 + excl;
    if (b == NBUCK - 1 && tid == 0) off[NN] = NE;
    __syncthreads();

    if (nr <= MAXB) {
        for (int i = tid; i < nr; i += 256) {
            const uint2 rr = rec[r0 + i];          // L2-hot second read
            const int ln = (rr.x >> 16) & 255;
            const int slot = atomicAdd(&cur[ln], 1);
            srt[slot] = (uint2){rr.x & 0xFFFFu, rr.y};
        }
        __syncthreads();
        for (int i = tid; i < nr; i += 256)        // linear coalesced flush
            rec2[r0 + i] = srt[i];
    } else {
        // overflow fallback (never expected on this graph): direct scatter
        for (int i = tid; i < nr; i += 256) {
            const uint2 rr = rec[r0 + i];
            const int ln = (rr.x >> 16) & 255;
            const int slot = atomicAdd(&cur[ln], 1);
            rec2[r0 + slot] = (uint2){rr.x & 0xFFFFu, rr.y};
        }
    }
}

// ---------------------------------------------------------------------------
// k3r: PURE aggregation. One wave per node, zero LDS, max occupancy.
//   Rb[n] = bf16( sum_e relu(Ab[n] + Bb[src] + ea*We2 + bp) )
// ---------------------------------------------------------------------------
__global__ __launch_bounds__(256, 8) void k3r_agg(
    const int* __restrict__ off, const uint2* __restrict__ rec2,
    const unsigned short* __restrict__ Ab, const unsigned short* __restrict__ Bb,
    const float* __restrict__ We2, const float* __restrict__ bp,
    unsigned short* __restrict__ Rb)
{
    const int j = threadIdx.x & 63;
    const int wid = (blockIdx.x * 256 + threadIdx.x) >> 6;
    const int nw = (gridDim.x * 256) >> 6;
    const float w0 = We2[j], w1 = We2[H + j], bpj = bp[j];

    for (int n = wid; n < NN; n += nw) {
        const int e0 = __builtin_amdgcn_readfirstlane(off[n]);
        const int e1 = __builtin_amdgcn_readfirstlane(off[n + 1]);
        const float a = bf2f(Ab[(size_t)n * H + j]) + bpj;
        float rsum = 0.f;

        auto proc = [&](unsigned rx, unsigned ry) {
            const float bb = bf2f(Bb[(size_t)(rx & 0xFFFFu) * H + j]);
            float z = a + bb;
            z = fmaf(__uint_as_float(ry << 16), w0, z);
            z = fmaf(__uint_as_float(ry & 0xFFFF0000u), w1, z);
            rsum += fmaxf(z, 0.f);
        };

        int e = e0;
        if ((e & 1) && e < e1) {
            const uint2 r = rec2[e];
            proc(r.x, r.y);
            ++e;
        }
        for (; e + 8 <= e1; e += 8) {
            const uint4 p0 = *(const uint4*)(rec2 + e);
            const uint4 p1 = *(const uint4*)(rec2 + e + 2);
            const uint4 p2 = *(const uint4*)(rec2 + e + 4);
            const uint4 p3 = *(const uint4*)(rec2 + e + 6);
            proc(p0.x, p0.y); proc(p0.z, p0.w);
            proc(p1.x, p1.y); proc(p1.z, p1.w);
            proc(p2.x, p2.y); proc(p2.z, p2.w);
            proc(p3.x, p3.y); proc(p3.z, p3.w);
        }
        for (; e + 2 <= e1; e += 2) {
            const uint4 p0 = *(const uint4*)(rec2 + e);
            proc(p0.x, p0.y); proc(p0.z, p0.w);
        }
        if (e < e1) {
            const uint2 r = rec2[e];
            proc(r.x, r.y);
        }
        Rb[(size_t)n * H + j] = f2bf(rsum);
    }
}

// ---------------------------------------------------------------------------
// k4_mfma: update MLP on matrix cores, 16-node tiles.
// ---------------------------------------------------------------------------
__global__ __launch_bounds__(256) void k4_mfma(
    const int* __restrict__ off,
    const unsigned short* __restrict__ Rb, const unsigned short* __restrict__ HUb,
    const float* __restrict__ Wma, const float* __restrict__ bma,
    const float* __restrict__ bu1,
    const float* __restrict__ Wu2, const float* __restrict__ bu2,
    float* __restrict__ out)
{
    __shared__ unsigned short hbuf[4][16 * 64];   // 8 KB
    __shared__ bf16x8 wfrag[2][4][2][64];         // 16 KB

    const int tid = threadIdx.x;
    const int w   = tid >> 6;
    const int l   = tid & 63;
    const int l15 = l & 15;
    const int lb  = l >> 4;

    if (w < 2) {
        const float* Wsrc = (w == 0) ? Wma : Wu2;
#pragma unroll
        for (int t = 0; t < 4; ++t)
#pragma unroll
            for (int kh = 0; kh < 2; ++kh) {
                bf16x8 f;
#pragma unroll
                for (int j = 0; j < 8; ++j) {
                    const int k = kh * 32 + lb * 8 + j;
                    f[j] = (short)f2bf(Wsrc[k * H + 16 * t + l15]);
                }
                wfrag[w][t][kh][l] = f;
            }
    }
    __syncthreads();

    const int g = blockIdx.x * 4 + w;
    if (g * 16 >= NN) return;
    const int n0 = g * 16;
    const f32x4 z4 = {0.f, 0.f, 0.f, 0.f};

    const bf16x8 r0 = *(const bf16x8*)(Rb + (size_t)(n0 + l15) * H + lb * 8);
    const bf16x8 r1 = *(const bf16x8*)(Rb + (size_t)(n0 + l15) * H + 32 + lb * 8);

    const float cntv = (float)(off[n0 + l15 + 1] - off[n0 + l15]);

    float bmat[4], bu1t[4], bu2t[4];
#pragma unroll
    for (int t = 0; t < 4; ++t) {
        bmat[t] = bma[16 * t + l15];
        bu1t[t] = bu1[16 * t + l15];
        bu2t[t] = bu2[16 * t + l15];
    }

#pragma unroll
    for (int t = 0; t < 4; ++t) {
        f32x4 acc = __builtin_amdgcn_mfma_f32_16x16x32_bf16(r0, wfrag[0][t][0][l], z4, 0, 0, 0);
        acc = __builtin_amdgcn_mfma_f32_16x16x32_bf16(r1, wfrag[0][t][1][l], acc, 0, 0, 0);
#pragma unroll
        for (int q = 0; q < 4; ++q) {
            const int row = lb * 4 + q;
            const float c  = __shfl(cntv, row, 64);
            const float cc = fmaxf(c, 1.0f);
            const float hu = bf2f(HUb[(size_t)(n0 + row) * H + 16 * t + l15]);
            float z = hu + fmaf(c, bmat[t], acc[q]) / cc + bu1t[t];
            z = fmaxf(z, 0.f);
            const int idx = (row * 64 + 16 * t + l15) ^ ((row & 7) << 3);
            hbuf[w][idx] = f2bf(z);
        }
    }
    __builtin_amdgcn_wave_barrier();

    const int ia0 = (l15 * 64 + 0  + lb * 8) ^ ((l15 & 7) << 3);
    const int ia1 = (l15 * 64 + 32 + lb * 8) ^ ((l15 & 7) << 3);
    const bf16x8 a0 = *reinterpret_cast<const bf16x8*>(&hbuf[w][ia0]);
    const bf16x8 a1 = *reinterpret_cast<const bf16x8*>(&hbuf[w][ia1]);

#pragma unroll
    for (int t = 0; t < 4; ++t) {
        f32x4 acc = __builtin_amdgcn_mfma_f32_16x16x32_bf16(a0, wfrag[1][t][0][l], z4, 0, 0, 0);
        acc = __builtin_amdgcn_mfma_f32_16x16x32_bf16(a1, wfrag[1][t][1][l], acc, 0, 0, 0);
#pragma unroll
        for (int q = 0; q < 4; ++q)
            out[(size_t)(n0 + lb * 4 + q) * H + 16 * t + l15] = acc[q] + bu2t[t];
    }
}

// ---------------------------------------------------------------------------
extern "C" void kernel_launch(void* const* d_in, const int* in_sizes, int n_in,
                              void* d_out, int out_size, void* d_ws, size_t ws_size,
                              hipStream_t stream) {
    (void)in_sizes; (void)n_in; (void)out_size; (void)ws_size;
    const float* x    = (const float*)d_in[0];
    const float* eatt = (const float*)d_in[1];
    const int*   eidx = (const int*)d_in[2];
    const float* Wn1  = (const float*)d_in[3];
    const float* bn1  = (const float*)d_in[4];
    const float* Wn2  = (const float*)d_in[5];
    const float* bn2  = (const float*)d_in[6];
    const float* We   = (const float*)d_in[7];
    const float* be   = (const float*)d_in[8];
    const float* Wm1  = (const float*)d_in[9];
    const float* bm1  = (const float*)d_in[10];
    const float* Wm2  = (const float*)d_in[11];
    const float* bm2  = (const float*)d_in[12];
    const float* Wu1  = (const float*)d_in[13];
    const float* bu1  = (const float*)d_in[14];
    const float* Wu2  = (const float*)d_in[15];
    const float* bu2  = (const float*)d_in[16];
    float* out = (float*)d_out;

    char* wsb = (char*)d_ws;
    unsigned short* Ab  = (unsigned short*)wsb;                    // NN*H bf16
    unsigned short* Bb  = Ab + (size_t)NN * H;                     // NN*H bf16
    unsigned short* HUb = Bb + (size_t)NN * H;                     // NN*H bf16
    unsigned short* Rb  = HUb + (size_t)NN * H;                    // NN*H bf16
    uint2* rec  = (uint2*)(Rb + (size_t)NN * H);                   // NE*8B
    uint2* rec2 = rec + NE;                                        // NE*8B
    int*   off  = (int*)(rec2 + NE);                               // NN+1
    int*   bbase= off + NN + 1;                                    // NBUCK+1
    int*   gbcnt= bbase + NBUCK + 1;                               // NBUCK
    int*   gcur = gbcnt + NBUCK;                                   // NBUCK
    float* We2  = (float*)(gcur + NBUCK);                          // 2*H
    float* bp   = We2 + 2 * H;                                     // H
    float* Wma  = bp + H;                                          // H*H
    float* bma  = Wma + H * H;                                     // H

    hipMemsetAsync(gbcnt, 0, NBUCK * sizeof(int), stream);

    kA_node_hist<<<K1B + HISTB, 256, 0, stream>>>(x, Wn1, bn1, Wn2, bn2,
                                                  Wm1, Wu1, eidx,
                                                  Ab, Bb, HUb, gbcnt);
    kB_scan_prep<<<1, 256, 0, stream>>>(gbcnt, bbase, gcur,
                                        We, be, Wm1, bm1, Wm2, bm2, Wu1,
                                        We2, bp, Wma, bma);
    k2s_sort<<<NCHUNK, 256, 0, stream>>>(eidx, eatt, gcur, rec);
    k2d_csr<<<NBUCK, 256, 0, stream>>>(bbase, rec, off, rec2);
    k3r_agg<<<2048, 256, 0, stream>>>(off, rec2, Ab, Bb, We2, bp, Rb);
    k4_mfma<<<(NN / 16 + 3) / 4, 256, 0, stream>>>(off, Rb, HUb, Wma, bma,
                                                   bu1, Wu2, bu2, out);
}